// Round 16
// baseline (264.206 us; speedup 1.0000x reference)
//
#include <hip/hip_runtime.h>
#include <cstdint>
#include <cstddef>

#define DD 1024
#define HD 64
#define NH 16
#define LTXT 512
#define LIMG 2048
#define LTOT 2560
#define DMLP 4096

typedef unsigned short u16;
typedef __attribute__((ext_vector_type(8))) __bf16 bf16x8;
typedef __attribute__((ext_vector_type(4))) float f32x4;

__device__ __forceinline__ u16 f2bf(float f) {
  union { float f; uint32_t u; } v; v.f = f;
  uint32_t r = v.u + 0x7FFFu + ((v.u >> 16) & 1u);
  return (u16)(r >> 16);
}
__device__ __forceinline__ float bf2f(u16 u) {
  union { uint32_t u; float f; } v; v.u = ((uint32_t)u) << 16;
  return v.f;
}
__device__ __forceinline__ uint32_t cvtpk(float lo, float hi) {
  uint32_t r;
  asm("v_cvt_pk_bf16_f32 %0, %1, %2" : "=v"(r) : "v"(lo), "v"(hi));
  return r;
}
// gelu via native sigmoid: 0.5x(1+tanh(z)) == x * sigmoid(2z)
__device__ __forceinline__ float geluf(float x) {
  const float u = fmaf(x * x, 0.044715f, 1.0f);
  const float e = __expf(x * u * -1.5957691216057308f);
  return x / (1.f + e);
}
__device__ __forceinline__ void gload16(const void* g, void* l) {
  __builtin_amdgcn_global_load_lds(
      (const __attribute__((address_space(1))) void*)g,
      (__attribute__((address_space(3))) void*)l, 16, 0, 0);
}
#define SWZ(row) (((((row) & 3) | ((((row) >> 3) & 1) << 2)) << 4))

// ------- fused weight transpose+cast: all 8 weight mats in one grid ---------
__global__ __launch_bounds__(256) void wcast_all(
    const float* __restrict__ s0, const float* __restrict__ s1,
    const float* __restrict__ s2, const float* __restrict__ s3,
    const float* __restrict__ s4, const float* __restrict__ s5,
    const float* __restrict__ s6, const float* __restrict__ s7,
    u16* __restrict__ d0, u16* __restrict__ d1, u16* __restrict__ d2,
    u16* __restrict__ d3, u16* __restrict__ d4, u16* __restrict__ d5,
    u16* __restrict__ d6, u16* __restrict__ d7) {
  const int b = blockIdx.x;
  const float* W; u16* Wt; int K, N, lb;
  if (b < 768)       { W = s0; Wt = d0; K = 1024; N = 3072; lb = b; }
  else if (b < 1536) { W = s1; Wt = d1; K = 1024; N = 3072; lb = b - 768; }
  else if (b < 1792) { W = s2; Wt = d2; K = 1024; N = 1024; lb = b - 1536; }
  else if (b < 2048) { W = s3; Wt = d3; K = 1024; N = 1024; lb = b - 1792; }
  else if (b < 3072) { W = s4; Wt = d4; K = 1024; N = 4096; lb = b - 2048; }
  else if (b < 4096) { W = s5; Wt = d5; K = 1024; N = 4096; lb = b - 3072; }
  else if (b < 5120) { W = s6; Wt = d6; K = 4096; N = 1024; lb = b - 4096; }
  else               { W = s7; Wt = d7; K = 4096; N = 1024; lb = b - 5120; }
  const int ntn = N >> 6;
  const int n0 = (lb % ntn) * 64, k0 = (lb / ntn) * 64;
  __shared__ float T[64][65];
  const int tx = threadIdx.x & 15, ty = threadIdx.x >> 4;
#pragma unroll
  for (int i = 0; i < 4; ++i) {
    const int r = ty + i * 16;
    const float4 v = *(const float4*)&W[(size_t)(k0 + r) * N + n0 + tx * 4];
    T[r][tx * 4 + 0] = v.x;
    T[r][tx * 4 + 1] = v.y;
    T[r][tx * 4 + 2] = v.z;
    T[r][tx * 4 + 3] = v.w;
  }
  __syncthreads();
  const int rn = threadIdx.x >> 2;
  const int cs = (threadIdx.x & 3) * 16;
  u16 buf[16];
#pragma unroll
  for (int j = 0; j < 16; ++j) buf[j] = f2bf(T[cs + j][rn]);
  u16* dst = &Wt[(size_t)(n0 + rn) * K + k0 + cs];
  *(uint4*)dst = *(uint4*)&buf[0];
  *(uint4*)(dst + 8) = *(uint4*)&buf[8];
}

// ---------------- mod GEMV split-K ------------------------------------------
__global__ __launch_bounds__(256) void mod_gemv_part(
    const float* __restrict__ vec, const float* __restrict__ wi,
    const float* __restrict__ wt, float* __restrict__ part) {
  __shared__ float sv[128];
  const int s = blockIdx.y, kc = blockIdx.z;
  const float* W = s ? wt : wi;
  if (threadIdx.x < 128) {
    float x = vec[kc * 128 + threadIdx.x];
    sv[threadIdx.x] = x / (1.f + __expf(-x));
  }
  __syncthreads();
  const int j = blockIdx.x * 256 + threadIdx.x;
  float acc = 0.f;
#pragma unroll 4
  for (int i = 0; i < 128; ++i)
    acc += sv[i] * W[(size_t)(kc * 128 + i) * 6144 + j];
  part[((size_t)(kc * 2 + s)) * 6144 + j] = acc;
}
__global__ __launch_bounds__(256) void mod_reduce(
    const float* __restrict__ part, const float* __restrict__ bi,
    const float* __restrict__ bt, float* __restrict__ modout) {
  const int idx = blockIdx.x * 256 + threadIdx.x;
  const int s = idx / 6144, j = idx % 6144;
  float a = s ? bt[j] : bi[j];
#pragma unroll
  for (int kc = 0; kc < 8; ++kc) a += part[((size_t)(kc * 2 + s)) * 6144 + j];
  modout[(size_t)s * 6144 + j] = a;
}

// ---------------- fused LN1 + modulate (txt+img, float4) --------------------
__global__ __launch_bounds__(256) void ln_mod2(
    const float* __restrict__ Xtxt, const float* __restrict__ Ximg,
    u16* __restrict__ out, const float* __restrict__ tns,
    const float* __restrict__ tnb, const float* __restrict__ ins,
    const float* __restrict__ inb, const float* __restrict__ modv) {
  __shared__ float red[8];
  const int r = blockIdx.x, tid = threadIdx.x;
  const float* x; const float* ns; const float* nb; const float* mv;
  if (r < LTXT) { x = Xtxt + (size_t)r * DD; ns = tns; nb = tnb; mv = modv + 6144; }
  else { x = Ximg + (size_t)(r - LTXT) * DD; ns = ins; nb = inb; mv = modv; }
  const int c0 = tid * 4;
  const float4 xv = *(const float4*)&x[c0];
  float v[4] = {xv.x, xv.y, xv.z, xv.w};
  float s = 0.f, sq = 0.f;
#pragma unroll
  for (int i = 0; i < 4; ++i) { s += v[i]; sq += v[i] * v[i]; }
#pragma unroll
  for (int o = 32; o; o >>= 1) {
    s += __shfl_xor(s, o);
    sq += __shfl_xor(sq, o);
  }
  if ((tid & 63) == 0) {
    red[tid >> 6] = s;
    red[4 + (tid >> 6)] = sq;
  }
  __syncthreads();
  s = red[0] + red[1] + red[2] + red[3];
  sq = red[4] + red[5] + red[6] + red[7];
  const float mu = s * (1.f / DD);
  const float var = sq * (1.f / DD) - mu * mu;
  const float rstd = rsqrtf(var + 1e-6f);
  const float4 nsv = *(const float4*)&ns[c0];
  const float4 nbv = *(const float4*)&nb[c0];
  const float4 shv = *(const float4*)&mv[c0];
  const float4 scv = *(const float4*)&mv[1024 + c0];
  const float nsa[4] = {nsv.x, nsv.y, nsv.z, nsv.w};
  const float nba[4] = {nbv.x, nbv.y, nbv.z, nbv.w};
  const float sha[4] = {shv.x, shv.y, shv.z, shv.w};
  const float sca[4] = {scv.x, scv.y, scv.z, scv.w};
  ushort4 o4;
  u16 ob[4];
#pragma unroll
  for (int i = 0; i < 4; ++i) {
    const float ln = (v[i] - mu) * rstd * nsa[i] + nba[i];
    ob[i] = f2bf((1.f + sca[i]) * ln + sha[i]);
  }
  o4.x = ob[0]; o4.y = ob[1]; o4.z = ob[2]; o4.w = ob[3];
  *(ushort4*)&out[(size_t)r * DD + c0] = o4;
}

// ------- fused residual1 + LN2 + modulate (txt+img, float4) -----------------
__global__ __launch_bounds__(256) void resid_ln2(
    const float* __restrict__ Xtxt, const float* __restrict__ Ximg,
    const u16* __restrict__ t, const float* __restrict__ modv,
    const float* __restrict__ tns, const float* __restrict__ tnb,
    const float* __restrict__ ins, const float* __restrict__ inb,
    float* __restrict__ otxt, float* __restrict__ oimg,
    u16* __restrict__ hout) {
  __shared__ float red[8];
  const int r = blockIdx.x, tid = threadIdx.x;
  const float* x; const float* ns; const float* nb; const float* mv; float* y;
  if (r < LTXT) {
    x = Xtxt + (size_t)r * DD; ns = tns; nb = tnb; mv = modv + 6144;
    y = otxt + (size_t)r * DD;
  } else {
    x = Ximg + (size_t)(r - LTXT) * DD; ns = ins; nb = inb; mv = modv;
    y = oimg + (size_t)(r - LTXT) * DD;
  }
  const int c0 = tid * 4;
  const float4 xv = *(const float4*)&x[c0];
  const ushort4 tb = *(const ushort4*)&t[(size_t)r * DD + c0];
  const float4 gv = *(const float4*)&mv[2048 + c0];
  float v[4];
  v[0] = xv.x + gv.x * bf2f(tb.x);
  v[1] = xv.y + gv.y * bf2f(tb.y);
  v[2] = xv.z + gv.z * bf2f(tb.z);
  v[3] = xv.w + gv.w * bf2f(tb.w);
  *(float4*)&y[c0] = *(float4*)v;
  float s = 0.f, sq = 0.f;
#pragma unroll
  for (int i = 0; i < 4; ++i) { s += v[i]; sq += v[i] * v[i]; }
#pragma unroll
  for (int o = 32; o; o >>= 1) {
    s += __shfl_xor(s, o);
    sq += __shfl_xor(sq, o);
  }
  if ((tid & 63) == 0) {
    red[tid >> 6] = s;
    red[4 + (tid >> 6)] = sq;
  }
  __syncthreads();
  s = red[0] + red[1] + red[2] + red[3];
  sq = red[4] + red[5] + red[6] + red[7];
  const float mu = s * (1.f / DD);
  const float var = sq * (1.f / DD) - mu * mu;
  const float rstd = rsqrtf(var + 1e-6f);
  const float4 nsv = *(const float4*)&ns[c0];
  const float4 nbv = *(const float4*)&nb[c0];
  const float4 shv = *(const float4*)&mv[3072 + c0];
  const float4 scv = *(const float4*)&mv[4096 + c0];
  const float nsa[4] = {nsv.x, nsv.y, nsv.z, nsv.w};
  const float nba[4] = {nbv.x, nbv.y, nbv.z, nbv.w};
  const float sha[4] = {shv.x, shv.y, shv.z, shv.w};
  const float sca[4] = {scv.x, scv.y, scv.z, scv.w};
  ushort4 o4;
  u16 ob[4];
#pragma unroll
  for (int i = 0; i < 4; ++i) {
    const float ln = (v[i] - mu) * rstd * nsa[i] + nba[i];
    ob[i] = f2bf((1.f + sca[i]) * ln + sha[i]);
  }
  o4.x = ob[0]; o4.y = ob[1]; o4.z = ob[2]; o4.w = ob[3];
  *(ushort4*)&hout[(size_t)r * DD + c0] = o4;
}

// --- bf16 MFMA GEMM, 128x128, BK=32, 8 waves (4x2 of 32x64), 2-buf 2-barrier
// Round-12 proven sync structure; 512 threads double waves/CU (10 -> 20).
__global__ __launch_bounds__(512) void gemm_pipe(
    const u16* __restrict__ A, const u16* __restrict__ BtT,
    const u16* __restrict__ BtI, const float* __restrict__ biasT,
    const float* __restrict__ biasI, u16* __restrict__ C,
    float* __restrict__ Cpart, int K, int Kblk, int N, int gelu) {
  __shared__ __align__(16) u16 As[2][128 * 32];
  __shared__ __align__(16) u16 Bs[2][128 * 32];
  const int tid = threadIdx.x, lane = tid & 63, wave = tid >> 6;  // 0..7
  const int nwg = gridDim.x * gridDim.y;
  const int orig = blockIdx.x + blockIdx.y * gridDim.x;
  const int lb = (orig & 7) * (nwg >> 3) + (orig >> 3);
  const int bn = lb / 20, bm = lb % 20;
  const int kc = blockIdx.z;
  const u16* Bt = (bm < (LTXT / 128)) ? BtT : BtI;
  const int wm = wave >> 1, wn = wave & 1;  // 4 x 2 wave grid
  const int lr = lane & 15, lk = lane >> 4;
  f32x4 acc[2][4] = {};
  const size_t a0 = (size_t)bm * 128;
  const size_t b0 = (size_t)bn * 128;
  const int kbase = kc * Kblk;
  const int NT = Kblk >> 5;
  const int srow = tid >> 2, soff = (tid & 3) * 8;  // 128 rows x 4 chunks

#define STAGE(t, buf)                                                         \
  {                                                                           \
    const int k0_ = kbase + (t) * 32;                                         \
    gload16(&A[(a0 + srow) * K + k0_ + soff], &As[buf][srow * 32 + soff]);    \
    gload16(&Bt[(b0 + srow) * K + k0_ + soff], &Bs[buf][srow * 32 + soff]);   \
  }

  STAGE(0, 0);
  STAGE(1, 1);
  for (int t = 0; t < NT; ++t) {
    if (t + 1 < NT) {
      asm volatile("s_waitcnt vmcnt(2)" ::: "memory");
    } else {
      asm volatile("s_waitcnt vmcnt(0)" ::: "memory");
    }
    __builtin_amdgcn_s_barrier();
    const int b = t & 1;
    bf16x8 af[2], bfv[4];
#pragma unroll
    for (int m = 0; m < 2; ++m)
      af[m] = *(const bf16x8*)&As[b][(wm * 32 + m * 16 + lr) * 32 + lk * 8];
#pragma unroll
    for (int n = 0; n < 4; ++n)
      bfv[n] = *(const bf16x8*)&Bs[b][(wn * 64 + n * 16 + lr) * 32 + lk * 8];
    asm volatile("s_waitcnt lgkmcnt(0)" ::: "memory");
    __builtin_amdgcn_sched_barrier(0);
    __builtin_amdgcn_s_barrier();
    if (t + 2 < NT) STAGE(t + 2, b);
    __builtin_amdgcn_sched_barrier(0);
    __builtin_amdgcn_s_setprio(1);
#pragma unroll
    for (int m = 0; m < 2; ++m)
#pragma unroll
      for (int n = 0; n < 4; ++n)
        acc[m][n] = __builtin_amdgcn_mfma_f32_16x16x32_bf16(af[m], bfv[n],
                                                            acc[m][n], 0, 0, 0);
    __builtin_amdgcn_s_setprio(0);
  }
#undef STAGE

  if (Cpart) {
    float* dst = Cpart + (size_t)kc * ((size_t)LTOT * N);
#pragma unroll
    for (int n = 0; n < 4; ++n) {
      const int col = bn * 128 + wn * 64 + n * 16 + lr;
#pragma unroll
      for (int m = 0; m < 2; ++m)
#pragma unroll
        for (int r = 0; r < 4; ++r) {
          const size_t row = a0 + wm * 32 + m * 16 + lk * 4 + r;
          dst[row * (size_t)N + col] = acc[m][n][r];
        }
    }
  } else {
    const float* bias = (bm < (LTXT / 128)) ? biasT : biasI;
#pragma unroll
    for (int n = 0; n < 4; ++n) {
      const int col = bn * 128 + wn * 64 + n * 16 + lr;
      const float bv = bias[col];
#pragma unroll
      for (int m = 0; m < 2; ++m)
#pragma unroll
        for (int r = 0; r < 4; ++r) {
          const size_t row = a0 + wm * 32 + m * 16 + lk * 4 + r;
          float v = acc[m][n][r] + bv;
          if (gelu) v = geluf(v);
          C[row * (size_t)N + col] = f2bf(v);
        }
    }
  }
}

// ---------------- split-K reduce: C = bf16(sum(part) + bias) ----------------
__global__ __launch_bounds__(256) void gemm_reduce(
    const float* __restrict__ part, const float* __restrict__ bT,
    const float* __restrict__ bI, u16* __restrict__ C, int N, int kcnt) {
  const size_t idx = (size_t)(blockIdx.x * 256 + threadIdx.x) * 4;
  const int row = (int)(idx / N), col = (int)(idx % N);
  float4 a = *(const float4*)&part[idx];
  for (int kc = 1; kc < kcnt; ++kc) {
    const float4 b = *(const float4*)&part[(size_t)kc * LTOT * N + idx];
    a.x += b.x; a.y += b.y; a.z += b.z; a.w += b.w;
  }
  const float* bias = (row < LTXT) ? bT : bI;
  ushort4 o;
  o.x = f2bf(a.x + bias[col]);
  o.y = f2bf(a.y + bias[col + 1]);
  o.z = f2bf(a.z + bias[col + 2]);
  o.w = f2bf(a.w + bias[col + 3]);
  *(ushort4*)&C[idx] = o;
}

// ------- MLP2 split-K reduce + bias + gated residual2 into d_out ------------
__global__ __launch_bounds__(256) void gemm_reduce_gate(
    const float* __restrict__ part, const float* __restrict__ bT,
    const float* __restrict__ bI, const float* __restrict__ modv,
    float* __restrict__ otxt, float* __restrict__ oimg, int kcnt) {
  const size_t idx = (size_t)(blockIdx.x * 256 + threadIdx.x) * 4;
  const int row = (int)(idx >> 10), col = (int)(idx & 1023);
  float4 a = *(const float4*)&part[idx];
  for (int kc = 1; kc < kcnt; ++kc) {
    const float4 b = *(const float4*)&part[(size_t)kc * LTOT * DD + idx];
    a.x += b.x; a.y += b.y; a.z += b.z; a.w += b.w;
  }
  const float* bias; const float* mv; float* o;
  if (row < LTXT) {
    bias = bT; mv = modv + 6144; o = otxt + (size_t)row * DD + col;
  } else {
    bias = bI; mv = modv; o = oimg + (size_t)(row - LTXT) * DD + col;
  }
  const float4 g = *(const float4*)&mv[5120 + col];
  const float4 cur = *(const float4*)o;
  float4 r;
  r.x = cur.x + g.x * (a.x + bias[col]);
  r.y = cur.y + g.y * (a.y + bias[col + 1]);
  r.z = cur.z + g.z * (a.z + bias[col + 2]);
  r.w = cur.w + g.w * (a.w + bias[col + 3]);
  *(float4*)o = r;
}

// ------- fused scatter + RMS + RoPE for q,k only (wave per (h,l)) -----------
__global__ __launch_bounds__(256) void scat_rope(
    const u16* __restrict__ qkv, u16* __restrict__ q, u16* __restrict__ k,
    const float* __restrict__ pe, const float* __restrict__ iqs,
    const float* __restrict__ iks, const float* __restrict__ tqs,
    const float* __restrict__ tks) {
  const int gw = (blockIdx.x * 256 + threadIdx.x) >> 6;
  const int lane = threadIdx.x & 63;
  const int l = gw % LTOT, h = gw / LTOT;
  const size_t rb = (size_t)l * 3072 + h * 64 + lane;
  const float qv = bf2f(qkv[rb]);
  const float kv = bf2f(qkv[rb + 1024]);
  const float* qs = (l < LTXT) ? tqs : iqs;
  const float* ks = (l < LTXT) ? tks : iks;
  const float* peb = pe + (size_t)l * 128 + (lane >> 1) * 4 + (lane & 1) * 2;
  const size_t base = ((size_t)h * LTOT + l) * HD + lane;
  {
    float ss = qv * qv;
#pragma unroll
    for (int o = 32; o; o >>= 1) ss += __shfl_xor(ss, o);
    float xn = qv * rsqrtf(ss * (1.f / HD) + 1e-6f) * qs[lane];
    float part = __shfl_xor(xn, 1);
    float x0 = (lane & 1) ? part : xn;
    float x1 = (lane & 1) ? xn : part;
    q[base] = f2bf(peb[0] * x0 + peb[1] * x1);
  }
  {
    float ss = kv * kv;
#pragma unroll
    for (int o = 32; o; o >>= 1) ss += __shfl_xor(ss, o);
    float xn = kv * rsqrtf(ss * (1.f / HD) + 1e-6f) * ks[lane];
    float part = __shfl_xor(xn, 1);
    float x0 = (lane & 1) ? part : xn;
    float x1 = (lane & 1) ? xn : part;
    k[base] = f2bf(peb[0] * x0 + peb[1] * x1);
  }
}

// ------- V transpose via LDS: qkv (L,3072) col-block -> VT (H,64,L) ---------
__global__ __launch_bounds__(256) void vt_build(const u16* __restrict__ qkv,
                                                u16* __restrict__ vt) {
  __shared__ u16 T[64][72];
  const int b = blockIdx.x;
  const int h = b & 15, lt = b >> 4;
  const int tid = threadIdx.x;
  const int r = tid >> 3, c8 = (tid & 7) * 8;
  const size_t srcbase = (size_t)(lt * 64) * 3072 + 2048 + h * 64;
  *(uint4*)&T[r][c8] = *(const uint4*)&qkv[srcbase + (size_t)r * 3072 + c8];
  *(uint4*)&T[r + 32][c8] =
      *(const uint4*)&qkv[srcbase + (size_t)(r + 32) * 3072 + c8];
  __syncthreads();
  const int d = tid >> 2, lc = (tid & 3) * 16;
  u16 buf[16];
#pragma unroll
  for (int j = 0; j < 16; ++j) buf[j] = T[lc + j][d];
  u16* dst = &vt[((size_t)h * 64 + d) * LTOT + lt * 64 + lc];
  *(uint4*)dst = *(uint4*)&buf[0];
  *(uint4*)(dst + 8) = *(uint4*)&buf[8];
}

// ---- MFMA flash attention: 8 waves x 16q, 128 q/block, split-KV {1,2,4} ----
template <int SPLIT>
__global__ __launch_bounds__(512) void attn_mfma(
    const u16* __restrict__ Q, const u16* __restrict__ Kg,
    const u16* __restrict__ VT, u16* __restrict__ out,
    float* __restrict__ part) {
  constexpr int LOG = (SPLIT == 4) ? 2 : ((SPLIT == 2) ? 1 : 0);
  __shared__ __align__(16) u16 Ks[2][64 * 64];
  __shared__ __align__(16) u16 Vs[2][64 * 64];
  const int tid = threadIdx.x, lane = tid & 63, w = tid >> 6;  // w = 0..7
  const int lr = lane & 15, lk = lane >> 4;
  const int blk = blockIdx.x;
  const int h = ((blk & 7) << 1) | ((blk >> 3) & 1);
  const int half = (blk >> 4) & (SPLIT - 1);
  const int q0 = (blk >> (4 + LOG)) * 128;
  const size_t hb = (size_t)h * LTOT;
  char* KsB0 = (char*)&Ks[0][0];
  char* VsB0 = (char*)&Vs[0][0];

  const int q = q0 + w * 16 + lr;
  const bf16x8 qa0 = *(const bf16x8*)&Q[(hb + q) * HD + lk * 8];
  const bf16x8 qa1 = *(const bf16x8*)&Q[(hb + q) * HD + 32 + lk * 8];

  const int srow = tid >> 3;  // 0..63
  const int soff = tid & 7;
  const int NT = (LTOT / SPLIT) / 64;
  const int kstart = half * (LTOT / SPLIT);

  float m_run = -1e30f, l_run = 0.f;
  f32x4 acc[4] = {};
  uint4 kst, vst;

  kst = *(const uint4*)&Kg[(hb + kstart + srow) * HD + soff * 8];
  vst = *(const uint4*)&VT[((size_t)h * HD + srow) * LTOT + kstart + soff * 8];
  *(uint4*)(KsB0 + ((srow * 128 + soff * 16) ^ SWZ(srow))) = kst;
  *(uint4*)(VsB0 + ((srow * 128 + soff * 16) ^ SWZ(srow))) = vst;
  __syncthreads();

  const float scale = 0.125f;
  for (int t = 0; t < NT; ++t) {
    char* KsC = KsB0 + (t & 1) * 8192;
    char* VsC = VsB0 + (t & 1) * 8192;
    if (t + 1 < NT) {
      const int k0n = kstart + (t + 1) * 64;
      kst = *(const uint4*)&Kg[(hb + k0n + srow) * HD + soff * 8];
      vst = *(const uint4*)&VT[((size_t)h * HD + srow) * LTOT + k0n + soff * 8];
    }
    f32x4 s[4];
    __builtin_amdgcn_s_setprio(1);
#pragma unroll
    for (int g = 0; g < 4; ++g) {
      const int kr = (lr >> 2) * 8 + (g & 1) * 4 + (lr & 3) + (g >> 1) * 32;
      const int sw = SWZ(kr);
      const bf16x8 ka0 = *(const bf16x8*)(KsC + ((kr * 128 + lk * 16) ^ sw));
      const bf16x8 ka1 = *(const bf16x8*)(KsC + ((kr * 128 + 64 + lk * 16) ^ sw));
      f32x4 z = {0.f, 0.f, 0.f, 0.f};
      z = __builtin_amdgcn_mfma_f32_16x16x32_bf16(ka0, qa0, z, 0, 0, 0);
      z = __builtin_amdgcn_mfma_f32_16x16x32_bf16(ka1, qa1, z, 0, 0, 0);
      s[g] = z;
    }
    __builtin_amdgcn_s_setprio(0);
    // tree max (depth 4, max3-fusable)
    float gm[4];
#pragma unroll
    for (int g = 0; g < 4; ++g)
      gm[g] = fmaxf(fmaxf(s[g][0], s[g][1]), fmaxf(s[g][2], s[g][3]));
    float tmax = fmaxf(fmaxf(gm[0], gm[1]), fmaxf(gm[2], gm[3]));
    tmax = fmaxf(tmax, __shfl_xor(tmax, 16));
    tmax = fmaxf(tmax, __shfl_xor(tmax, 32));
    tmax *= scale;
    if (!__all(tmax <= m_run + 8.f)) {
      const float mnew = fmaxf(m_run, tmax);
      const float alpha = __expf(m_run - mnew);
      l_run *= alpha;
#pragma unroll
      for (int dt = 0; dt < 4; ++dt) {
        acc[dt][0] *= alpha;
        acc[dt][1] *= alpha;
        acc[dt][2] *= alpha;
        acc[dt][3] *= alpha;
      }
      m_run = mnew;
    }
    float p[4][4];
    float psum = 0.f;
#pragma unroll
    for (int g = 0; g < 4; ++g)
#pragma unroll
      for (int r = 0; r < 4; ++r) {
        p[g][r] = __expf(s[g][r] * scale - m_run);
        psum += p[g][r];
      }
    psum += __shfl_xor(psum, 16);
    psum += __shfl_xor(psum, 32);
    l_run += psum;
    union { uint32_t u[4]; bf16x8 v; } pb0, pb1;
    pb0.u[0] = cvtpk(p[0][0], p[0][1]);
    pb0.u[1] = cvtpk(p[0][2], p[0][3]);
    pb0.u[2] = cvtpk(p[1][0], p[1][1]);
    pb0.u[3] = cvtpk(p[1][2], p[1][3]);
    pb1.u[0] = cvtpk(p[2][0], p[2][1]);
    pb1.u[1] = cvtpk(p[2][2], p[2][3]);
    pb1.u[2] = cvtpk(p[3][0], p[3][1]);
    pb1.u[3] = cvtpk(p[3][2], p[3][3]);
    __builtin_amdgcn_s_setprio(1);
#pragma unroll
    for (int dt = 0; dt < 4; ++dt) {
      const int vr = dt * 16 + lr;
      const int sw = SWZ(vr);
      const bf16x8 va0 = *(const bf16x8*)(VsC + ((vr * 128 + lk * 16) ^ sw));
      const bf16x8 va1 = *(const bf16x8*)(VsC + ((vr * 128 + 64 + lk * 16) ^ sw));
      acc[dt] = __builtin_amdgcn_mfma_f32_16x16x32_bf16(va0, pb0.v, acc[dt], 0, 0, 0);
      acc[dt] = __builtin_amdgcn_mfma_f32_16x16x32_bf16(va1, pb1.v, acc[dt], 0, 0, 0);
    }
    __builtin_amdgcn_s_setprio(0);
    if (t + 1 < NT) {
      char* KsN = KsB0 + ((t + 1) & 1) * 8192;
      char* VsN = VsB0 + ((t + 1) & 1) * 8192;
      *(uint4*)(KsN + ((srow * 128 + soff * 16) ^ SWZ(srow))) = kst;
      *(uint4*)(VsN + ((srow * 128 + soff * 16) ^ SWZ(srow))) = vst;
      __syncthreads();
    }
  }
  if (SPLIT > 1) {
    float* pr = part + (((size_t)(half * LTOT) + q) * 16 + h) * 68;
#pragma unroll
    for (int dt = 0; dt < 4; ++dt)
      *(f32x4*)&pr[dt * 16 + lk * 4] = acc[dt];
    if (lk == 0) {
      pr[64] = m_run;
      pr[65] = l_run;
    }
  } else {
    __syncthreads();
    const float inv = 1.f / l_run;
    char* ob = KsB0 + w * 2048;
    const int esw = (lr & 7) << 4;
#pragma unroll
    for (int dt = 0; dt < 4; ++dt) {
      const uint32_t a = cvtpk(acc[dt][0] * inv, acc[dt][1] * inv);
      const uint32_t b2 = cvtpk(acc[dt][2] * inv, acc[dt][3] * inv);
      const int ad = lr * 128 + dt * 32 + lk * 8;
      *(uint32_t*)(ob + (ad ^ esw)) = a;
      *(uint32_t*)(ob + ((ad + 4) ^ esw)) = b2;
    }
    __syncthreads();
    const int row = lane >> 2, ch = lane & 3;
    const int rsw = (row & 7) << 4;
    const uint4 o0 = *(const uint4*)(ob + ((row * 128 + ch * 32) ^ rsw));
    const uint4 o1 = *(const uint4*)(ob + ((row * 128 + ch * 32 + 16) ^ rsw));
    u16* orow = &out[(size_t)(q0 + w * 16 + row) * DD + h * HD + ch * 16];
    *(uint4*)orow = o0;
    *(uint4*)(orow + 8) = o1;
  }
}

// ---------------- merge SPLIT KV parts -> bf16 out (L,1024) -----------------
template <int SPLIT>
__global__ __launch_bounds__(256) void attn_merge(const float* __restrict__ part,
                                                  u16* __restrict__ out) {
  const int idx = blockIdx.x * 256 + threadIdx.x;
  const int d4 = idx & 15, h = (idx >> 4) & 15, q = idx >> 8;
  size_t base[SPLIT];
  float ms[SPLIT], ls[SPLIT];
  float m = -1e30f;
#pragma unroll
  for (int s = 0; s < SPLIT; ++s) {
    base[s] = (((size_t)(s * LTOT) + q) * 16 + h) * 68;
    ms[s] = part[base[s] + 64];
    ls[s] = part[base[s] + 65];
    m = fmaxf(m, ms[s]);
  }
  float denom = 0.f;
  float a[SPLIT];
#pragma unroll
  for (int s = 0; s < SPLIT; ++s) {
    a[s] = __expf(ms[s] - m);
    denom += ls[s] * a[s];
  }
  const float inv = 1.f / denom;
  float r[4] = {0.f, 0.f, 0.f, 0.f};
#pragma unroll
  for (int s = 0; s < SPLIT; ++s) {
    const float4 x = *(const float4*)&part[base[s] + d4 * 4];
    const float sc = a[s] * inv;
    r[0] += x.x * sc; r[1] += x.y * sc; r[2] += x.z * sc; r[3] += x.w * sc;
  }
  uint2 o;
  o.x = cvtpk(r[0], r[1]);
  o.y = cvtpk(r[2], r[3]);
  *(uint2*)&out[(size_t)q * DD + h * HD + d4 * 4] = o;
}

// ---------------- gated residual (fallback path only) -----------------------
__global__ __launch_bounds__(256) void resid_gate(
    const float* __restrict__ xin, const u16* __restrict__ t,
    const float* __restrict__ g, float* __restrict__ out, int n4) {
  const int idx = blockIdx.x * 256 + threadIdx.x;
  if (idx >= n4) return;
  const int col = (idx * 4) & (DD - 1);
  const float4 a = ((const float4*)xin)[idx];
  const ushort4 tb = ((const ushort4*)t)[idx];
  const float4 gg = *(const float4*)&g[col];
  float4 r;
  r.x = a.x + gg.x * bf2f(tb.x);
  r.y = a.y + gg.y * bf2f(tb.y);
  r.z = a.z + gg.z * bf2f(tb.z);
  r.w = a.w + gg.w * bf2f(tb.w);
  ((float4*)out)[idx] = r;
}

extern "C" void kernel_launch(void* const* d_in, const int* in_sizes, int n_in,
                              void* d_out, int out_size, void* d_ws,
                              size_t ws_size, hipStream_t stream) {
  const float* img = (const float*)d_in[0];
  const float* txt = (const float*)d_in[1];
  const float* vec = (const float*)d_in[2];
  const float* pe = (const float*)d_in[3];
  const float* i_mod_w = (const float*)d_in[4];
  const float* i_mod_b = (const float*)d_in[5];
  const float* i_n1s = (const float*)d_in[6];
  const float* i_n1b = (const float*)d_in[7];
  const float* i_qkv_w = (const float*)d_in[8];
  const float* i_qkv_b = (const float*)d_in[9];
  const float* i_qs = (const float*)d_in[10];
  const float* i_ks = (const float*)d_in[11];
  const float* i_proj_w = (const float*)d_in[12];
  const float* i_proj_b = (const float*)d_in[13];
  const float* i_n2s = (const float*)d_in[14];
  const float* i_n2b = (const float*)d_in[15];
  const float* i_w1 = (const float*)d_in[16];
  const float* i_b1 = (const float*)d_in[17];
  const float* i_w2 = (const float*)d_in[18];
  const float* i_b2 = (const float*)d_in[19];
  const float* t_mod_w = (const float*)d_in[20];
  const float* t_mod_b = (const float*)d_in[21];
  const float* t_n1s = (const float*)d_in[22];
  const float* t_n1b = (const float*)d_in[23];
  const float* t_qkv_w = (const float*)d_in[24];
  const float* t_qkv_b = (const float*)d_in[25];
  const float* t_qs = (const float*)d_in[26];
  const float* t_ks = (const float*)d_in[27];
  const float* t_proj_w = (const float*)d_in[28];
  const float* t_proj_b = (const float*)d_in[29];
  const float* t_n2s = (const float*)d_in[30];
  const float* t_n2b = (const float*)d_in[31];
  const float* t_w1 = (const float*)d_in[32];
  const float* t_b1 = (const float*)d_in[33];
  const float* t_w2 = (const float*)d_in[34];
  const float* t_b2 = (const float*)d_in[35];

  const size_t LD = (size_t)LTOT * DD;
  uint8_t* p = (uint8_t*)d_ws;
  float* modb = (float*)p;           p += 64 * 1024;
  float* part = (float*)p;           p += 512 * 1024;
  u16* tqkvT = (u16*)p;              p += (size_t)3072 * 1024 * 2;
  u16* iqkvT = (u16*)p;              p += (size_t)3072 * 1024 * 2;
  u16* tprojT = (u16*)p;             p += (size_t)1024 * 1024 * 2;
  u16* iprojT = (u16*)p;             p += (size_t)1024 * 1024 * 2;
  u16* tw1T = (u16*)p;               p += (size_t)4096 * 1024 * 2;
  u16* iw1T = (u16*)p;               p += (size_t)4096 * 1024 * 2;
  u16* tw2T = (u16*)p;               p += (size_t)1024 * 4096 * 2;
  u16* iw2T = (u16*)p;               p += (size_t)1024 * 4096 * 2;
  u16* actA = (u16*)p;               p += LD * 2;
  u16* actB = (u16*)p;               p += (size_t)LTOT * DMLP * 2;
  u16* actC = (u16*)p;               p += LD * 2 * 3;
  float* gpart = (float*)p;
  const size_t used = (size_t)(p - (uint8_t*)d_ws);
  const size_t avail = ws_size > used ? ws_size - used : 0;
  const size_t attn_need2 = (size_t)2 * LTOT * 16 * 68 * sizeof(float);
  const size_t attn_need4 = 2 * attn_need2;
  const int attn_split = avail >= attn_need4 ? 4 : (avail >= attn_need2 ? 2 : 1);
  const int kc_proj = avail >= 2 * LD * sizeof(float) ? 2 : 1;
  const int kc_mlp2 = avail >= 4 * LD * sizeof(float)
                          ? 4
                          : (avail >= 2 * LD * sizeof(float) ? 2 : 1);
  float* out_img = (float*)d_out;
  float* out_txt = out_img + (size_t)LIMG * DD;

  // 0. weight transpose+cast
  wcast_all<<<6144, 256, 0, stream>>>(t_qkv_w, i_qkv_w, t_proj_w, i_proj_w,
                                      t_w1, i_w1, t_w2, i_w2, tqkvT, iqkvT,
                                      tprojT, iprojT, tw1T, iw1T, tw2T, iw2T);
  // 1. modulation
  mod_gemv_part<<<dim3(24, 2, 8), 256, 0, stream>>>(vec, i_mod_w, t_mod_w, part);
  mod_reduce<<<48, 256, 0, stream>>>(part, i_mod_b, t_mod_b, modb);
  // 2. LN1+mod -> actA
  ln_mod2<<<LTOT, 256, 0, stream>>>(txt, img, actA, t_n1s, t_n1b, i_n1s, i_n1b,
                                    modb);
  // 3. QKV GEMM -> actB
  gemm_pipe<<<dim3(24, 20, 1), 512, 0, stream>>>(actA, tqkvT, iqkvT, t_qkv_b,
                                                 i_qkv_b, actB, nullptr, 1024,
                                                 1024, 3072, 0);
  // 4. q,k scatter + RMS + RoPE ; V transpose
  scat_rope<<<10240, 256, 0, stream>>>(actB, actC, actC + LD, pe, i_qs, i_ks,
                                       t_qs, t_ks);
  vt_build<<<640, 256, 0, stream>>>(actB, actC + 2 * LD);
  // 6. attention (8 waves x 16q, split-KV) -> actA
  if (attn_split == 4) {
    attn_mfma<4><<<1280, 512, 0, stream>>>(actC, actC + LD, actC + 2 * LD,
                                           actA, gpart);
    attn_merge<4><<<2560, 256, 0, stream>>>(gpart, actA);
  } else if (attn_split == 2) {
    attn_mfma<2><<<640, 512, 0, stream>>>(actC, actC + LD, actC + 2 * LD,
                                          actA, gpart);
    attn_merge<2><<<2560, 256, 0, stream>>>(gpart, actA);
  } else {
    attn_mfma<1><<<320, 512, 0, stream>>>(actC, actC + LD, actC + 2 * LD, actA,
                                          nullptr);
  }
  // 7. proj GEMM (split-K) -> actC
  if (kc_proj > 1) {
    gemm_pipe<<<dim3(8, 20, kc_proj), 512, 0, stream>>>(
        actA, tprojT, iprojT, nullptr, nullptr, nullptr, gpart, 1024,
        1024 / kc_proj, 1024, 0);
    gemm_reduce<<<2560, 256, 0, stream>>>(gpart, t_proj_b, i_proj_b, actC,
                                          1024, kc_proj);
  } else {
    gemm_pipe<<<dim3(8, 20, 1), 512, 0, stream>>>(actA, tprojT, iprojT,
                                                  t_proj_b, i_proj_b, actC,
                                                  nullptr, 1024, 1024, 1024, 0);
  }
  // 8+9. fused residual1 + LN2+mod
  resid_ln2<<<LTOT, 256, 0, stream>>>(txt, img, actC, modb, t_n2s, t_n2b,
                                      i_n2s, i_n2b, out_txt, out_img,
                                      actC + LD);
  // 10. MLP1+GELU -> actB
  gemm_pipe<<<dim3(32, 20, 1), 512, 0, stream>>>(actC + LD, tw1T, iw1T, t_b1,
                                                 i_b1, actB, nullptr, 1024,
                                                 1024, 4096, 1);
  // 11+12. MLP2 (split-K) + fused reduce+bias+gate residual2 -> d_out
  if (kc_mlp2 > 1) {
    gemm_pipe<<<dim3(8, 20, kc_mlp2), 512, 0, stream>>>(
        actB, tw2T, iw2T, nullptr, nullptr, nullptr, gpart, 4096,
        4096 / kc_mlp2, 1024, 0);
    gemm_reduce_gate<<<2560, 256, 0, stream>>>(gpart, t_b2, i_b2, modb,
                                               out_txt, out_img, kc_mlp2);
  } else {
    gemm_pipe<<<dim3(8, 20, 1), 512, 0, stream>>>(actB, tw2T, iw2T, t_b2, i_b2,
                                                  actC + 2 * LD, nullptr, 4096,
                                                  4096, 1024, 0);
    resid_gate<<<2048, 256, 0, stream>>>(out_img,
                                         actC + 2 * LD + (size_t)LTXT * DD,
                                         modb + 5120, out_img, LIMG * DD / 4);
    resid_gate<<<512, 256, 0, stream>>>(out_txt, actC + 2 * LD,
                                        modb + 6144 + 5120, out_txt,
                                        LTXT * DD / 4);
  }
}

// Round 17
// 258.829 us; speedup vs baseline: 1.0208x; 1.0208x over previous
//
#include <hip/hip_runtime.h>
#include <cstdint>
#include <cstddef>

#define DD 1024
#define HD 64
#define NH 16
#define LTXT 512
#define LIMG 2048
#define LTOT 2560
#define DMLP 4096

typedef unsigned short u16;
typedef __attribute__((ext_vector_type(8))) __bf16 bf16x8;
typedef __attribute__((ext_vector_type(4))) float f32x4;

__device__ __forceinline__ u16 f2bf(float f) {
  union { float f; uint32_t u; } v; v.f = f;
  uint32_t r = v.u + 0x7FFFu + ((v.u >> 16) & 1u);
  return (u16)(r >> 16);
}
__device__ __forceinline__ float bf2f(u16 u) {
  union { uint32_t u; float f; } v; v.u = ((uint32_t)u) << 16;
  return v.f;
}
__device__ __forceinline__ uint32_t cvtpk(float lo, float hi) {
  uint32_t r;
  asm("v_cvt_pk_bf16_f32 %0, %1, %2" : "=v"(r) : "v"(lo), "v"(hi));
  return r;
}
// native v_exp_f32 (2^x) — NOT libm exp2f (round-6 regression trap)
__device__ __forceinline__ float fexp2(float x) {
  return __builtin_amdgcn_exp2f(x);
}
// gelu via native sigmoid: 0.5x(1+tanh(z)) == x * sigmoid(2z)
__device__ __forceinline__ float geluf(float x) {
  const float u = fmaf(x * x, 0.044715f, 1.0f);
  const float e = __expf(x * u * -1.5957691216057308f);
  return x / (1.f + e);
}
__device__ __forceinline__ void gload16(const void* g, void* l) {
  __builtin_amdgcn_global_load_lds(
      (const __attribute__((address_space(1))) void*)g,
      (__attribute__((address_space(3))) void*)l, 16, 0, 0);
}
#define SWZ(row) (((((row) & 3) | ((((row) >> 3) & 1) << 2)) << 4))

// ------- fused weight transpose+cast: all 8 weight mats in one grid ---------
__global__ __launch_bounds__(256) void wcast_all(
    const float* __restrict__ s0, const float* __restrict__ s1,
    const float* __restrict__ s2, const float* __restrict__ s3,
    const float* __restrict__ s4, const float* __restrict__ s5,
    const float* __restrict__ s6, const float* __restrict__ s7,
    u16* __restrict__ d0, u16* __restrict__ d1, u16* __restrict__ d2,
    u16* __restrict__ d3, u16* __restrict__ d4, u16* __restrict__ d5,
    u16* __restrict__ d6, u16* __restrict__ d7) {
  const int b = blockIdx.x;
  const float* W; u16* Wt; int K, N, lb;
  if (b < 768)       { W = s0; Wt = d0; K = 1024; N = 3072; lb = b; }
  else if (b < 1536) { W = s1; Wt = d1; K = 1024; N = 3072; lb = b - 768; }
  else if (b < 1792) { W = s2; Wt = d2; K = 1024; N = 1024; lb = b - 1536; }
  else if (b < 2048) { W = s3; Wt = d3; K = 1024; N = 1024; lb = b - 1792; }
  else if (b < 3072) { W = s4; Wt = d4; K = 1024; N = 4096; lb = b - 2048; }
  else if (b < 4096) { W = s5; Wt = d5; K = 1024; N = 4096; lb = b - 3072; }
  else if (b < 5120) { W = s6; Wt = d6; K = 4096; N = 1024; lb = b - 4096; }
  else               { W = s7; Wt = d7; K = 4096; N = 1024; lb = b - 5120; }
  const int ntn = N >> 6;
  const int n0 = (lb % ntn) * 64, k0 = (lb / ntn) * 64;
  __shared__ float T[64][65];
  const int tx = threadIdx.x & 15, ty = threadIdx.x >> 4;
#pragma unroll
  for (int i = 0; i < 4; ++i) {
    const int r = ty + i * 16;
    const float4 v = *(const float4*)&W[(size_t)(k0 + r) * N + n0 + tx * 4];
    T[r][tx * 4 + 0] = v.x;
    T[r][tx * 4 + 1] = v.y;
    T[r][tx * 4 + 2] = v.z;
    T[r][tx * 4 + 3] = v.w;
  }
  __syncthreads();
  const int rn = threadIdx.x >> 2;
  const int cs = (threadIdx.x & 3) * 16;
  u16 buf[16];
#pragma unroll
  for (int j = 0; j < 16; ++j) buf[j] = f2bf(T[cs + j][rn]);
  u16* dst = &Wt[(size_t)(n0 + rn) * K + k0 + cs];
  *(uint4*)dst = *(uint4*)&buf[0];
  *(uint4*)(dst + 8) = *(uint4*)&buf[8];
}

// ---------------- mod GEMV split-K ------------------------------------------
__global__ __launch_bounds__(256) void mod_gemv_part(
    const float* __restrict__ vec, const float* __restrict__ wi,
    const float* __restrict__ wt, float* __restrict__ part) {
  __shared__ float sv[128];
  const int s = blockIdx.y, kc = blockIdx.z;
  const float* W = s ? wt : wi;
  if (threadIdx.x < 128) {
    float x = vec[kc * 128 + threadIdx.x];
    sv[threadIdx.x] = x / (1.f + __expf(-x));
  }
  __syncthreads();
  const int j = blockIdx.x * 256 + threadIdx.x;
  float acc = 0.f;
#pragma unroll 4
  for (int i = 0; i < 128; ++i)
    acc += sv[i] * W[(size_t)(kc * 128 + i) * 6144 + j];
  part[((size_t)(kc * 2 + s)) * 6144 + j] = acc;
}
__global__ __launch_bounds__(256) void mod_reduce(
    const float* __restrict__ part, const float* __restrict__ bi,
    const float* __restrict__ bt, float* __restrict__ modout) {
  const int idx = blockIdx.x * 256 + threadIdx.x;
  const int s = idx / 6144, j = idx % 6144;
  float a = s ? bt[j] : bi[j];
#pragma unroll
  for (int kc = 0; kc < 8; ++kc) a += part[((size_t)(kc * 2 + s)) * 6144 + j];
  modout[(size_t)s * 6144 + j] = a;
}

// ---------------- fused LN1 + modulate (txt+img, float4) --------------------
__global__ __launch_bounds__(256) void ln_mod2(
    const float* __restrict__ Xtxt, const float* __restrict__ Ximg,
    u16* __restrict__ out, const float* __restrict__ tns,
    const float* __restrict__ tnb, const float* __restrict__ ins,
    const float* __restrict__ inb, const float* __restrict__ modv) {
  __shared__ float red[8];
  const int r = blockIdx.x, tid = threadIdx.x;
  const float* x; const float* ns; const float* nb; const float* mv;
  if (r < LTXT) { x = Xtxt + (size_t)r * DD; ns = tns; nb = tnb; mv = modv + 6144; }
  else { x = Ximg + (size_t)(r - LTXT) * DD; ns = ins; nb = inb; mv = modv; }
  const int c0 = tid * 4;
  const float4 xv = *(const float4*)&x[c0];
  float v[4] = {xv.x, xv.y, xv.z, xv.w};
  float s = 0.f, sq = 0.f;
#pragma unroll
  for (int i = 0; i < 4; ++i) { s += v[i]; sq += v[i] * v[i]; }
#pragma unroll
  for (int o = 32; o; o >>= 1) {
    s += __shfl_xor(s, o);
    sq += __shfl_xor(sq, o);
  }
  if ((tid & 63) == 0) {
    red[tid >> 6] = s;
    red[4 + (tid >> 6)] = sq;
  }
  __syncthreads();
  s = red[0] + red[1] + red[2] + red[3];
  sq = red[4] + red[5] + red[6] + red[7];
  const float mu = s * (1.f / DD);
  const float var = sq * (1.f / DD) - mu * mu;
  const float rstd = rsqrtf(var + 1e-6f);
  const float4 nsv = *(const float4*)&ns[c0];
  const float4 nbv = *(const float4*)&nb[c0];
  const float4 shv = *(const float4*)&mv[c0];
  const float4 scv = *(const float4*)&mv[1024 + c0];
  const float nsa[4] = {nsv.x, nsv.y, nsv.z, nsv.w};
  const float nba[4] = {nbv.x, nbv.y, nbv.z, nbv.w};
  const float sha[4] = {shv.x, shv.y, shv.z, shv.w};
  const float sca[4] = {scv.x, scv.y, scv.z, scv.w};
  ushort4 o4;
  u16 ob[4];
#pragma unroll
  for (int i = 0; i < 4; ++i) {
    const float ln = (v[i] - mu) * rstd * nsa[i] + nba[i];
    ob[i] = f2bf((1.f + sca[i]) * ln + sha[i]);
  }
  o4.x = ob[0]; o4.y = ob[1]; o4.z = ob[2]; o4.w = ob[3];
  *(ushort4*)&out[(size_t)r * DD + c0] = o4;
}

// ------- fused residual1 + LN2 + modulate (txt+img, float4) -----------------
__global__ __launch_bounds__(256) void resid_ln2(
    const float* __restrict__ Xtxt, const float* __restrict__ Ximg,
    const u16* __restrict__ t, const float* __restrict__ modv,
    const float* __restrict__ tns, const float* __restrict__ tnb,
    const float* __restrict__ ins, const float* __restrict__ inb,
    float* __restrict__ otxt, float* __restrict__ oimg,
    u16* __restrict__ hout) {
  __shared__ float red[8];
  const int r = blockIdx.x, tid = threadIdx.x;
  const float* x; const float* ns; const float* nb; const float* mv; float* y;
  if (r < LTXT) {
    x = Xtxt + (size_t)r * DD; ns = tns; nb = tnb; mv = modv + 6144;
    y = otxt + (size_t)r * DD;
  } else {
    x = Ximg + (size_t)(r - LTXT) * DD; ns = ins; nb = inb; mv = modv;
    y = oimg + (size_t)(r - LTXT) * DD;
  }
  const int c0 = tid * 4;
  const float4 xv = *(const float4*)&x[c0];
  const ushort4 tb = *(const ushort4*)&t[(size_t)r * DD + c0];
  const float4 gv = *(const float4*)&mv[2048 + c0];
  float v[4];
  v[0] = xv.x + gv.x * bf2f(tb.x);
  v[1] = xv.y + gv.y * bf2f(tb.y);
  v[2] = xv.z + gv.z * bf2f(tb.z);
  v[3] = xv.w + gv.w * bf2f(tb.w);
  *(float4*)&y[c0] = *(float4*)v;
  float s = 0.f, sq = 0.f;
#pragma unroll
  for (int i = 0; i < 4; ++i) { s += v[i]; sq += v[i] * v[i]; }
#pragma unroll
  for (int o = 32; o; o >>= 1) {
    s += __shfl_xor(s, o);
    sq += __shfl_xor(sq, o);
  }
  if ((tid & 63) == 0) {
    red[tid >> 6] = s;
    red[4 + (tid >> 6)] = sq;
  }
  __syncthreads();
  s = red[0] + red[1] + red[2] + red[3];
  sq = red[4] + red[5] + red[6] + red[7];
  const float mu = s * (1.f / DD);
  const float var = sq * (1.f / DD) - mu * mu;
  const float rstd = rsqrtf(var + 1e-6f);
  const float4 nsv = *(const float4*)&ns[c0];
  const float4 nbv = *(const float4*)&nb[c0];
  const float4 shv = *(const float4*)&mv[3072 + c0];
  const float4 scv = *(const float4*)&mv[4096 + c0];
  const float nsa[4] = {nsv.x, nsv.y, nsv.z, nsv.w};
  const float nba[4] = {nbv.x, nbv.y, nbv.z, nbv.w};
  const float sha[4] = {shv.x, shv.y, shv.z, shv.w};
  const float sca[4] = {scv.x, scv.y, scv.z, scv.w};
  ushort4 o4;
  u16 ob[4];
#pragma unroll
  for (int i = 0; i < 4; ++i) {
    const float ln = (v[i] - mu) * rstd * nsa[i] + nba[i];
    ob[i] = f2bf((1.f + sca[i]) * ln + sha[i]);
  }
  o4.x = ob[0]; o4.y = ob[1]; o4.z = ob[2]; o4.w = ob[3];
  *(ushort4*)&hout[(size_t)r * DD + c0] = o4;
}

// --- bf16 MFMA GEMM, 128x128, BK=32, 8 waves (4x2 of 32x64), 2-buf 2-barrier
__global__ __launch_bounds__(512) void gemm_pipe(
    const u16* __restrict__ A, const u16* __restrict__ BtT,
    const u16* __restrict__ BtI, const float* __restrict__ biasT,
    const float* __restrict__ biasI, u16* __restrict__ C,
    float* __restrict__ Cpart, int K, int Kblk, int N, int gelu) {
  __shared__ __align__(16) u16 As[2][128 * 32];
  __shared__ __align__(16) u16 Bs[2][128 * 32];
  const int tid = threadIdx.x, lane = tid & 63, wave = tid >> 6;  // 0..7
  const int nwg = gridDim.x * gridDim.y;
  const int orig = blockIdx.x + blockIdx.y * gridDim.x;
  const int lb = (orig & 7) * (nwg >> 3) + (orig >> 3);
  const int bn = lb / 20, bm = lb % 20;
  const int kc = blockIdx.z;
  const u16* Bt = (bm < (LTXT / 128)) ? BtT : BtI;
  const int wm = wave >> 1, wn = wave & 1;  // 4 x 2 wave grid
  const int lr = lane & 15, lk = lane >> 4;
  f32x4 acc[2][4] = {};
  const size_t a0 = (size_t)bm * 128;
  const size_t b0 = (size_t)bn * 128;
  const int kbase = kc * Kblk;
  const int NT = Kblk >> 5;
  const int srow = tid >> 2, soff = (tid & 3) * 8;  // 128 rows x 4 chunks

#define STAGE(t, buf)                                                         \
  {                                                                           \
    const int k0_ = kbase + (t) * 32;                                         \
    gload16(&A[(a0 + srow) * K + k0_ + soff], &As[buf][srow * 32 + soff]);    \
    gload16(&Bt[(b0 + srow) * K + k0_ + soff], &Bs[buf][srow * 32 + soff]);   \
  }

  STAGE(0, 0);
  STAGE(1, 1);
  for (int t = 0; t < NT; ++t) {
    if (t + 1 < NT) {
      asm volatile("s_waitcnt vmcnt(2)" ::: "memory");
    } else {
      asm volatile("s_waitcnt vmcnt(0)" ::: "memory");
    }
    __builtin_amdgcn_s_barrier();
    const int b = t & 1;
    bf16x8 af[2], bfv[4];
#pragma unroll
    for (int m = 0; m < 2; ++m)
      af[m] = *(const bf16x8*)&As[b][(wm * 32 + m * 16 + lr) * 32 + lk * 8];
#pragma unroll
    for (int n = 0; n < 4; ++n)
      bfv[n] = *(const bf16x8*)&Bs[b][(wn * 64 + n * 16 + lr) * 32 + lk * 8];
    asm volatile("s_waitcnt lgkmcnt(0)" ::: "memory");
    __builtin_amdgcn_sched_barrier(0);
    __builtin_amdgcn_s_barrier();
    if (t + 2 < NT) STAGE(t + 2, b);
    __builtin_amdgcn_sched_barrier(0);
    __builtin_amdgcn_s_setprio(1);
#pragma unroll
    for (int m = 0; m < 2; ++m)
#pragma unroll
      for (int n = 0; n < 4; ++n)
        acc[m][n] = __builtin_amdgcn_mfma_f32_16x16x32_bf16(af[m], bfv[n],
                                                            acc[m][n], 0, 0, 0);
    __builtin_amdgcn_s_setprio(0);
  }
#undef STAGE

  if (Cpart) {
    float* dst = Cpart + (size_t)kc * ((size_t)LTOT * N);
#pragma unroll
    for (int n = 0; n < 4; ++n) {
      const int col = bn * 128 + wn * 64 + n * 16 + lr;
#pragma unroll
      for (int m = 0; m < 2; ++m)
#pragma unroll
        for (int r = 0; r < 4; ++r) {
          const size_t row = a0 + wm * 32 + m * 16 + lk * 4 + r;
          dst[row * (size_t)N + col] = acc[m][n][r];
        }
    }
  } else {
    const float* bias = (bm < (LTXT / 128)) ? biasT : biasI;
#pragma unroll
    for (int n = 0; n < 4; ++n) {
      const int col = bn * 128 + wn * 64 + n * 16 + lr;
      const float bv = bias[col];
#pragma unroll
      for (int m = 0; m < 2; ++m)
#pragma unroll
        for (int r = 0; r < 4; ++r) {
          const size_t row = a0 + wm * 32 + m * 16 + lk * 4 + r;
          float v = acc[m][n][r] + bv;
          if (gelu) v = geluf(v);
          C[row * (size_t)N + col] = f2bf(v);
        }
    }
  }
}

// ---------------- split-K reduce: C = bf16(sum(part) + bias) ----------------
__global__ __launch_bounds__(256) void gemm_reduce(
    const float* __restrict__ part, const float* __restrict__ bT,
    const float* __restrict__ bI, u16* __restrict__ C, int N, int kcnt) {
  const size_t idx = (size_t)(blockIdx.x * 256 + threadIdx.x) * 4;
  const int row = (int)(idx / N), col = (int)(idx % N);
  float4 a = *(const float4*)&part[idx];
  for (int kc = 1; kc < kcnt; ++kc) {
    const float4 b = *(const float4*)&part[(size_t)kc * LTOT * N + idx];
    a.x += b.x; a.y += b.y; a.z += b.z; a.w += b.w;
  }
  const float* bias = (row < LTXT) ? bT : bI;
  ushort4 o;
  o.x = f2bf(a.x + bias[col]);
  o.y = f2bf(a.y + bias[col + 1]);
  o.z = f2bf(a.z + bias[col + 2]);
  o.w = f2bf(a.w + bias[col + 3]);
  *(ushort4*)&C[idx] = o;
}

// ------- MLP2 split-K reduce + bias + gated residual2 into d_out ------------
__global__ __launch_bounds__(256) void gemm_reduce_gate(
    const float* __restrict__ part, const float* __restrict__ bT,
    const float* __restrict__ bI, const float* __restrict__ modv,
    float* __restrict__ otxt, float* __restrict__ oimg, int kcnt) {
  const size_t idx = (size_t)(blockIdx.x * 256 + threadIdx.x) * 4;
  const int row = (int)(idx >> 10), col = (int)(idx & 1023);
  float4 a = *(const float4*)&part[idx];
  for (int kc = 1; kc < kcnt; ++kc) {
    const float4 b = *(const float4*)&part[(size_t)kc * LTOT * DD + idx];
    a.x += b.x; a.y += b.y; a.z += b.z; a.w += b.w;
  }
  const float* bias; const float* mv; float* o;
  if (row < LTXT) {
    bias = bT; mv = modv + 6144; o = otxt + (size_t)row * DD + col;
  } else {
    bias = bI; mv = modv; o = oimg + (size_t)(row - LTXT) * DD + col;
  }
  const float4 g = *(const float4*)&mv[5120 + col];
  const float4 cur = *(const float4*)o;
  float4 r;
  r.x = cur.x + g.x * (a.x + bias[col]);
  r.y = cur.y + g.y * (a.y + bias[col + 1]);
  r.z = cur.z + g.z * (a.z + bias[col + 2]);
  r.w = cur.w + g.w * (a.w + bias[col + 3]);
  *(float4*)o = r;
}

// ------- fused scatter + RMS + RoPE for q,k (wave per (h,l)) ----------------
// q is pre-scaled by 0.125*log2(e) so attention softmax runs in exp2 domain.
__global__ __launch_bounds__(256) void scat_rope(
    const u16* __restrict__ qkv, u16* __restrict__ q, u16* __restrict__ k,
    const float* __restrict__ pe, const float* __restrict__ iqs,
    const float* __restrict__ iks, const float* __restrict__ tqs,
    const float* __restrict__ tks) {
  const int gw = (blockIdx.x * 256 + threadIdx.x) >> 6;
  const int lane = threadIdx.x & 63;
  const int l = gw % LTOT, h = gw / LTOT;
  const size_t rb = (size_t)l * 3072 + h * 64 + lane;
  const float qv = bf2f(qkv[rb]);
  const float kv = bf2f(qkv[rb + 1024]);
  const float* qs = (l < LTXT) ? tqs : iqs;
  const float* ks = (l < LTXT) ? tks : iks;
  const float* peb = pe + (size_t)l * 128 + (lane >> 1) * 4 + (lane & 1) * 2;
  const size_t base = ((size_t)h * LTOT + l) * HD + lane;
  {
    float ss = qv * qv;
#pragma unroll
    for (int o = 32; o; o >>= 1) ss += __shfl_xor(ss, o);
    float xn = qv * rsqrtf(ss * (1.f / HD) + 1e-6f) * qs[lane];
    float part = __shfl_xor(xn, 1);
    float x0 = (lane & 1) ? part : xn;
    float x1 = (lane & 1) ? xn : part;
    q[base] = f2bf((peb[0] * x0 + peb[1] * x1) * 0.1803368801111f);
  }
  {
    float ss = kv * kv;
#pragma unroll
    for (int o = 32; o; o >>= 1) ss += __shfl_xor(ss, o);
    float xn = kv * rsqrtf(ss * (1.f / HD) + 1e-6f) * ks[lane];
    float part = __shfl_xor(xn, 1);
    float x0 = (lane & 1) ? part : xn;
    float x1 = (lane & 1) ? xn : part;
    k[base] = f2bf(peb[0] * x0 + peb[1] * x1);
  }
}

// ------- V transpose via LDS: qkv (L,3072) col-block -> VT (H,64,L) ---------
__global__ __launch_bounds__(256) void vt_build(const u16* __restrict__ qkv,
                                                u16* __restrict__ vt) {
  __shared__ u16 T[64][72];
  const int b = blockIdx.x;
  const int h = b & 15, lt = b >> 4;
  const int tid = threadIdx.x;
  const int r = tid >> 3, c8 = (tid & 7) * 8;
  const size_t srcbase = (size_t)(lt * 64) * 3072 + 2048 + h * 64;
  *(uint4*)&T[r][c8] = *(const uint4*)&qkv[srcbase + (size_t)r * 3072 + c8];
  *(uint4*)&T[r + 32][c8] =
      *(const uint4*)&qkv[srcbase + (size_t)(r + 32) * 3072 + c8];
  __syncthreads();
  const int d = tid >> 2, lc = (tid & 3) * 16;
  u16 buf[16];
#pragma unroll
  for (int j = 0; j < 16; ++j) buf[j] = T[lc + j][d];
  u16* dst = &vt[((size_t)h * 64 + d) * LTOT + lt * 64 + lc];
  *(uint4*)dst = *(uint4*)&buf[0];
  *(uint4*)(dst + 8) = *(uint4*)&buf[8];
}

// ---- MFMA flash attention: 8 waves x 16q, 128 q/block, split-KV {1,2,4} ----
// exp2-domain softmax (Q pre-scaled); SPLIT>1 partials: 64 bf16 + f32 m,l
// per (q,h) in stride-80 u16 rows.
template <int SPLIT>
__global__ __launch_bounds__(512) void attn_mfma(
    const u16* __restrict__ Q, const u16* __restrict__ Kg,
    const u16* __restrict__ VT, u16* __restrict__ out,
    u16* __restrict__ part) {
  constexpr int LOG = (SPLIT == 4) ? 2 : ((SPLIT == 2) ? 1 : 0);
  __shared__ __align__(16) u16 Ks[2][64 * 64];
  __shared__ __align__(16) u16 Vs[2][64 * 64];
  const int tid = threadIdx.x, lane = tid & 63, w = tid >> 6;  // w = 0..7
  const int lr = lane & 15, lk = lane >> 4;
  const int blk = blockIdx.x;
  const int h = ((blk & 7) << 1) | ((blk >> 3) & 1);
  const int half = (blk >> 4) & (SPLIT - 1);
  const int q0 = (blk >> (4 + LOG)) * 128;
  const size_t hb = (size_t)h * LTOT;
  char* KsB0 = (char*)&Ks[0][0];
  char* VsB0 = (char*)&Vs[0][0];

  const int q = q0 + w * 16 + lr;
  const bf16x8 qa0 = *(const bf16x8*)&Q[(hb + q) * HD + lk * 8];
  const bf16x8 qa1 = *(const bf16x8*)&Q[(hb + q) * HD + 32 + lk * 8];

  const int srow = tid >> 3;  // 0..63
  const int soff = tid & 7;
  const int NT = (LTOT / SPLIT) / 64;
  const int kstart = half * (LTOT / SPLIT);

  float m_run = -1e30f, l_run = 0.f;
  f32x4 acc[4] = {};
  uint4 kst, vst;

  kst = *(const uint4*)&Kg[(hb + kstart + srow) * HD + soff * 8];
  vst = *(const uint4*)&VT[((size_t)h * HD + srow) * LTOT + kstart + soff * 8];
  *(uint4*)(KsB0 + ((srow * 128 + soff * 16) ^ SWZ(srow))) = kst;
  *(uint4*)(VsB0 + ((srow * 128 + soff * 16) ^ SWZ(srow))) = vst;
  __syncthreads();

  for (int t = 0; t < NT; ++t) {
    char* KsC = KsB0 + (t & 1) * 8192;
    char* VsC = VsB0 + (t & 1) * 8192;
    if (t + 1 < NT) {
      const int k0n = kstart + (t + 1) * 64;
      kst = *(const uint4*)&Kg[(hb + k0n + srow) * HD + soff * 8];
      vst = *(const uint4*)&VT[((size_t)h * HD + srow) * LTOT + k0n + soff * 8];
    }
    f32x4 s[4];
    __builtin_amdgcn_s_setprio(1);
#pragma unroll
    for (int g = 0; g < 4; ++g) {
      const int kr = (lr >> 2) * 8 + (g & 1) * 4 + (lr & 3) + (g >> 1) * 32;
      const int sw = SWZ(kr);
      const bf16x8 ka0 = *(const bf16x8*)(KsC + ((kr * 128 + lk * 16) ^ sw));
      const bf16x8 ka1 = *(const bf16x8*)(KsC + ((kr * 128 + 64 + lk * 16) ^ sw));
      f32x4 z = {0.f, 0.f, 0.f, 0.f};
      z = __builtin_amdgcn_mfma_f32_16x16x32_bf16(ka0, qa0, z, 0, 0, 0);
      z = __builtin_amdgcn_mfma_f32_16x16x32_bf16(ka1, qa1, z, 0, 0, 0);
      s[g] = z;
    }
    __builtin_amdgcn_s_setprio(0);
    // tree max (depth 4, max3-fusable); scores already in log2 units
    float gm[4];
#pragma unroll
    for (int g = 0; g < 4; ++g)
      gm[g] = fmaxf(fmaxf(s[g][0], s[g][1]), fmaxf(s[g][2], s[g][3]));
    float tmax = fmaxf(fmaxf(gm[0], gm[1]), fmaxf(gm[2], gm[3]));
    tmax = fmaxf(tmax, __shfl_xor(tmax, 16));
    tmax = fmaxf(tmax, __shfl_xor(tmax, 32));
    if (!__all(tmax <= m_run + 11.5415603f)) {  // 8 nats in log2
      const float mnew = fmaxf(m_run, tmax);
      const float alpha = fexp2(m_run - mnew);
      l_run *= alpha;
#pragma unroll
      for (int dt = 0; dt < 4; ++dt) {
        acc[dt][0] *= alpha;
        acc[dt][1] *= alpha;
        acc[dt][2] *= alpha;
        acc[dt][3] *= alpha;
      }
      m_run = mnew;
    }
    float p[4][4];
    float psum = 0.f;
#pragma unroll
    for (int g = 0; g < 4; ++g)
#pragma unroll
      for (int r = 0; r < 4; ++r) {
        p[g][r] = fexp2(s[g][r] - m_run);
        psum += p[g][r];
      }
    psum += __shfl_xor(psum, 16);
    psum += __shfl_xor(psum, 32);
    l_run += psum;
    union { uint32_t u[4]; bf16x8 v; } pb0, pb1;
    pb0.u[0] = cvtpk(p[0][0], p[0][1]);
    pb0.u[1] = cvtpk(p[0][2], p[0][3]);
    pb0.u[2] = cvtpk(p[1][0], p[1][1]);
    pb0.u[3] = cvtpk(p[1][2], p[1][3]);
    pb1.u[0] = cvtpk(p[2][0], p[2][1]);
    pb1.u[1] = cvtpk(p[2][2], p[2][3]);
    pb1.u[2] = cvtpk(p[3][0], p[3][1]);
    pb1.u[3] = cvtpk(p[3][2], p[3][3]);
    __builtin_amdgcn_s_setprio(1);
#pragma unroll
    for (int dt = 0; dt < 4; ++dt) {
      const int vr = dt * 16 + lr;
      const int sw = SWZ(vr);
      const bf16x8 va0 = *(const bf16x8*)(VsC + ((vr * 128 + lk * 16) ^ sw));
      const bf16x8 va1 = *(const bf16x8*)(VsC + ((vr * 128 + 64 + lk * 16) ^ sw));
      acc[dt] = __builtin_amdgcn_mfma_f32_16x16x32_bf16(va0, pb0.v, acc[dt], 0, 0, 0);
      acc[dt] = __builtin_amdgcn_mfma_f32_16x16x32_bf16(va1, pb1.v, acc[dt], 0, 0, 0);
    }
    __builtin_amdgcn_s_setprio(0);
    if (t + 1 < NT) {
      char* KsN = KsB0 + ((t + 1) & 1) * 8192;
      char* VsN = VsB0 + ((t + 1) & 1) * 8192;
      *(uint4*)(KsN + ((srow * 128 + soff * 16) ^ SWZ(srow))) = kst;
      *(uint4*)(VsN + ((srow * 128 + soff * 16) ^ SWZ(srow))) = vst;
      __syncthreads();
    }
  }
  if (SPLIT > 1) {
    u16* pr = part + (((size_t)(half * LTOT) + q) * 16 + h) * 80;
#pragma unroll
    for (int dt = 0; dt < 4; ++dt) {
      uint2 o;
      o.x = cvtpk(acc[dt][0], acc[dt][1]);
      o.y = cvtpk(acc[dt][2], acc[dt][3]);
      *(uint2*)&pr[dt * 16 + lk * 4] = o;
    }
    if (lk == 0) {
      *(float*)&pr[64] = m_run;
      *(float*)&pr[66] = l_run;
    }
  } else {
    __syncthreads();
    const float inv = 1.f / l_run;
    char* ob = KsB0 + w * 2048;
    const int esw = (lr & 7) << 4;
#pragma unroll
    for (int dt = 0; dt < 4; ++dt) {
      const uint32_t a = cvtpk(acc[dt][0] * inv, acc[dt][1] * inv);
      const uint32_t b2 = cvtpk(acc[dt][2] * inv, acc[dt][3] * inv);
      const int ad = lr * 128 + dt * 32 + lk * 8;
      *(uint32_t*)(ob + (ad ^ esw)) = a;
      *(uint32_t*)(ob + ((ad + 4) ^ esw)) = b2;
    }
    __syncthreads();
    const int row = lane >> 2, ch = lane & 3;
    const int rsw = (row & 7) << 4;
    const uint4 o0 = *(const uint4*)(ob + ((row * 128 + ch * 32) ^ rsw));
    const uint4 o1 = *(const uint4*)(ob + ((row * 128 + ch * 32 + 16) ^ rsw));
    u16* orow = &out[(size_t)(q0 + w * 16 + row) * DD + h * HD + ch * 16];
    *(uint4*)orow = o0;
    *(uint4*)(orow + 8) = o1;
  }
}

// ---------------- merge SPLIT KV parts (bf16) -> bf16 out (L,1024) ----------
template <int SPLIT>
__global__ __launch_bounds__(256) void attn_merge(const u16* __restrict__ part,
                                                  u16* __restrict__ out) {
  const int idx = blockIdx.x * 256 + threadIdx.x;
  const int d4 = idx & 15, h = (idx >> 4) & 15, q = idx >> 8;
  const u16* bp[SPLIT];
  float ms[SPLIT], ls[SPLIT];
  float m = -1e30f;
#pragma unroll
  for (int s = 0; s < SPLIT; ++s) {
    bp[s] = part + (((size_t)(s * LTOT) + q) * 16 + h) * 80;
    ms[s] = *(const float*)&bp[s][64];
    ls[s] = *(const float*)&bp[s][66];
    m = fmaxf(m, ms[s]);
  }
  float denom = 0.f;
  float a[SPLIT];
#pragma unroll
  for (int s = 0; s < SPLIT; ++s) {
    a[s] = fexp2(ms[s] - m);
    denom += ls[s] * a[s];
  }
  const float inv = 1.f / denom;
  float r[4] = {0.f, 0.f, 0.f, 0.f};
#pragma unroll
  for (int s = 0; s < SPLIT; ++s) {
    const uint2 xr = *(const uint2*)&bp[s][d4 * 4];
    const u16* xp = (const u16*)&xr;
    const float sc = a[s] * inv;
    r[0] += bf2f(xp[0]) * sc;
    r[1] += bf2f(xp[1]) * sc;
    r[2] += bf2f(xp[2]) * sc;
    r[3] += bf2f(xp[3]) * sc;
  }
  uint2 o;
  o.x = cvtpk(r[0], r[1]);
  o.y = cvtpk(r[2], r[3]);
  *(uint2*)&out[(size_t)q * DD + h * HD + d4 * 4] = o;
}

// ---------------- gated residual (fallback path only) -----------------------
__global__ __launch_bounds__(256) void resid_gate(
    const float* __restrict__ xin, const u16* __restrict__ t,
    const float* __restrict__ g, float* __restrict__ out, int n4) {
  const int idx = blockIdx.x * 256 + threadIdx.x;
  if (idx >= n4) return;
  const int col = (idx * 4) & (DD - 1);
  const float4 a = ((const float4*)xin)[idx];
  const ushort4 tb = ((const ushort4*)t)[idx];
  const float4 gg = *(const float4*)&g[col];
  float4 r;
  r.x = a.x + gg.x * bf2f(tb.x);
  r.y = a.y + gg.y * bf2f(tb.y);
  r.z = a.z + gg.z * bf2f(tb.z);
  r.w = a.w + gg.w * bf2f(tb.w);
  ((float4*)out)[idx] = r;
}

extern "C" void kernel_launch(void* const* d_in, const int* in_sizes, int n_in,
                              void* d_out, int out_size, void* d_ws,
                              size_t ws_size, hipStream_t stream) {
  const float* img = (const float*)d_in[0];
  const float* txt = (const float*)d_in[1];
  const float* vec = (const float*)d_in[2];
  const float* pe = (const float*)d_in[3];
  const float* i_mod_w = (const float*)d_in[4];
  const float* i_mod_b = (const float*)d_in[5];
  const float* i_n1s = (const float*)d_in[6];
  const float* i_n1b = (const float*)d_in[7];
  const float* i_qkv_w = (const float*)d_in[8];
  const float* i_qkv_b = (const float*)d_in[9];
  const float* i_qs = (const float*)d_in[10];
  const float* i_ks = (const float*)d_in[11];
  const float* i_proj_w = (const float*)d_in[12];
  const float* i_proj_b = (const float*)d_in[13];
  const float* i_n2s = (const float*)d_in[14];
  const float* i_n2b = (const float*)d_in[15];
  const float* i_w1 = (const float*)d_in[16];
  const float* i_b1 = (const float*)d_in[17];
  const float* i_w2 = (const float*)d_in[18];
  const float* i_b2 = (const float*)d_in[19];
  const float* t_mod_w = (const float*)d_in[20];
  const float* t_mod_b = (const float*)d_in[21];
  const float* t_n1s = (const float*)d_in[22];
  const float* t_n1b = (const float*)d_in[23];
  const float* t_qkv_w = (const float*)d_in[24];
  const float* t_qkv_b = (const float*)d_in[25];
  const float* t_qs = (const float*)d_in[26];
  const float* t_ks = (const float*)d_in[27];
  const float* t_proj_w = (const float*)d_in[28];
  const float* t_proj_b = (const float*)d_in[29];
  const float* t_n2s = (const float*)d_in[30];
  const float* t_n2b = (const float*)d_in[31];
  const float* t_w1 = (const float*)d_in[32];
  const float* t_b1 = (const float*)d_in[33];
  const float* t_w2 = (const float*)d_in[34];
  const float* t_b2 = (const float*)d_in[35];

  const size_t LD = (size_t)LTOT * DD;
  uint8_t* p = (uint8_t*)d_ws;
  float* modb = (float*)p;           p += 64 * 1024;
  float* part = (float*)p;           p += 512 * 1024;
  u16* tqkvT = (u16*)p;              p += (size_t)3072 * 1024 * 2;
  u16* iqkvT = (u16*)p;              p += (size_t)3072 * 1024 * 2;
  u16* tprojT = (u16*)p;             p += (size_t)1024 * 1024 * 2;
  u16* iprojT = (u16*)p;             p += (size_t)1024 * 1024 * 2;
  u16* tw1T = (u16*)p;               p += (size_t)4096 * 1024 * 2;
  u16* iw1T = (u16*)p;               p += (size_t)4096 * 1024 * 2;
  u16* tw2T = (u16*)p;               p += (size_t)1024 * 4096 * 2;
  u16* iw2T = (u16*)p;               p += (size_t)1024 * 4096 * 2;
  u16* actA = (u16*)p;               p += LD * 2;
  u16* actB = (u16*)p;               p += (size_t)LTOT * DMLP * 2;
  u16* actC = (u16*)p;               p += LD * 2 * 3;
  float* gpart = (float*)p;
  const size_t used = (size_t)(p - (uint8_t*)d_ws);
  const size_t avail = ws_size > used ? ws_size - used : 0;
  const size_t attn_need2 = (size_t)2 * LTOT * 16 * 80 * sizeof(u16);
  const size_t attn_need4 = 2 * attn_need2;
  const int attn_split = avail >= attn_need4 ? 4 : (avail >= attn_need2 ? 2 : 1);
  const int kc_proj = avail >= 2 * LD * sizeof(float) ? 2 : 1;
  const int kc_mlp2 = avail >= 4 * LD * sizeof(float)
                          ? 4
                          : (avail >= 2 * LD * sizeof(float) ? 2 : 1);
  float* out_img = (float*)d_out;
  float* out_txt = out_img + (size_t)LIMG * DD;

  // 0. weight transpose+cast
  wcast_all<<<6144, 256, 0, stream>>>(t_qkv_w, i_qkv_w, t_proj_w, i_proj_w,
                                      t_w1, i_w1, t_w2, i_w2, tqkvT, iqkvT,
                                      tprojT, iprojT, tw1T, iw1T, tw2T, iw2T);
  // 1. modulation
  mod_gemv_part<<<dim3(24, 2, 8), 256, 0, stream>>>(vec, i_mod_w, t_mod_w, part);
  mod_reduce<<<48, 256, 0, stream>>>(part, i_mod_b, t_mod_b, modb);
  // 2. LN1+mod -> actA
  ln_mod2<<<LTOT, 256, 0, stream>>>(txt, img, actA, t_n1s, t_n1b, i_n1s, i_n1b,
                                    modb);
  // 3. QKV GEMM -> actB
  gemm_pipe<<<dim3(24, 20, 1), 512, 0, stream>>>(actA, tqkvT, iqkvT, t_qkv_b,
                                                 i_qkv_b, actB, nullptr, 1024,
                                                 1024, 3072, 0);
  // 4. q,k scatter + RMS + RoPE ; V transpose
  scat_rope<<<10240, 256, 0, stream>>>(actB, actC, actC + LD, pe, i_qs, i_ks,
                                       t_qs, t_ks);
  vt_build<<<640, 256, 0, stream>>>(actB, actC + 2 * LD);
  // 6. attention (8 waves x 16q, split-KV) -> actA
  if (attn_split == 4) {
    attn_mfma<4><<<1280, 512, 0, stream>>>(actC, actC + LD, actC + 2 * LD,
                                           actA, (u16*)gpart);
    attn_merge<4><<<2560, 256, 0, stream>>>((const u16*)gpart, actA);
  } else if (attn_split == 2) {
    attn_mfma<2><<<640, 512, 0, stream>>>(actC, actC + LD, actC + 2 * LD,
                                          actA, (u16*)gpart);
    attn_merge<2><<<2560, 256, 0, stream>>>((const u16*)gpart, actA);
  } else {
    attn_mfma<1><<<320, 512, 0, stream>>>(actC, actC + LD, actC + 2 * LD, actA,
                                          nullptr);
  }
  // 7. proj GEMM (split-K) -> actC
  if (kc_proj > 1) {
    gemm_pipe<<<dim3(8, 20, kc_proj), 512, 0, stream>>>(
        actA, tprojT, iprojT, nullptr, nullptr, nullptr, gpart, 1024,
        1024 / kc_proj, 1024, 0);
    gemm_reduce<<<2560, 256, 0, stream>>>(gpart, t_proj_b, i_proj_b, actC,
                                          1024, kc_proj);
  } else {
    gemm_pipe<<<dim3(8, 20, 1), 512, 0, stream>>>(actA, tprojT, iprojT,
                                                  t_proj_b, i_proj_b, actC,
                                                  nullptr, 1024, 1024, 1024, 0);
  }
  // 8+9. fused residual1 + LN2+mod
  resid_ln2<<<LTOT, 256, 0, stream>>>(txt, img, actC, modb, t_n2s, t_n2b,
                                      i_n2s, i_n2b, out_txt, out_img,
                                      actC + LD);
  // 10. MLP1+GELU -> actB
  gemm_pipe<<<dim3(32, 20, 1), 512, 0, stream>>>(actC + LD, tw1T, iw1T, t_b1,
                                                 i_b1, actB, nullptr, 1024,
                                                 1024, 4096, 1);
  // 11+12. MLP2 (split-K) + fused reduce+bias+gate residual2 -> d_out
  if (kc_mlp2 > 1) {
    gemm_pipe<<<dim3(8, 20, kc_mlp2), 512, 0, stream>>>(
        actB, tw2T, iw2T, nullptr, nullptr, nullptr, gpart, 4096,
        4096 / kc_mlp2, 1024, 0);
    gemm_reduce_gate<<<2560, 256, 0, stream>>>(gpart, t_b2, i_b2, modb,
                                               out_txt, out_img, kc_mlp2);
  } else {
    gemm_pipe<<<dim3(8, 20, 1), 512, 0, stream>>>(actB, tw2T, iw2T, t_b2, i_b2,
                                                  actC + 2 * LD, nullptr, 4096,
                                                  4096, 1024, 0);
    resid_gate<<<2048, 256, 0, stream>>>(out_img,
                                         actC + 2 * LD + (size_t)LTXT * DD,
                                         modb + 5120, out_img, LIMG * DD / 4);
    resid_gate<<<512, 256, 0, stream>>>(out_txt, actC + 2 * LD,
                                        modb + 6144 + 5120, out_txt,
                                        LTXT * DD / 4);
  }
}

// Round 18
// 256.322 us; speedup vs baseline: 1.0308x; 1.0098x over previous
//
#include <hip/hip_runtime.h>
#include <cstdint>
#include <cstddef>

#define DD 1024
#define HD 64
#define NH 16
#define LTXT 512
#define LIMG 2048
#define LTOT 2560
#define DMLP 4096

typedef unsigned short u16;
typedef __attribute__((ext_vector_type(8))) __bf16 bf16x8;
typedef __attribute__((ext_vector_type(4))) float f32x4;

__device__ __forceinline__ u16 f2bf(float f) {
  union { float f; uint32_t u; } v; v.f = f;
  uint32_t r = v.u + 0x7FFFu + ((v.u >> 16) & 1u);
  return (u16)(r >> 16);
}
__device__ __forceinline__ float bf2f(u16 u) {
  union { uint32_t u; float f; } v; v.u = ((uint32_t)u) << 16;
  return v.f;
}
__device__ __forceinline__ uint32_t cvtpk(float lo, float hi) {
  uint32_t r;
  asm("v_cvt_pk_bf16_f32 %0, %1, %2" : "=v"(r) : "v"(lo), "v"(hi));
  return r;
}
// native v_exp_f32 (2^x) — NOT libm exp2f (round-6 regression trap)
__device__ __forceinline__ float fexp2(float x) {
  return __builtin_amdgcn_exp2f(x);
}
// gelu via native sigmoid: 0.5x(1+tanh(z)) == x * sigmoid(2z)
__device__ __forceinline__ float geluf(float x) {
  const float u = fmaf(x * x, 0.044715f, 1.0f);
  const float e = __expf(x * u * -1.5957691216057308f);
  return x / (1.f + e);
}
__device__ __forceinline__ void gload16(const void* g, void* l) {
  __builtin_amdgcn_global_load_lds(
      (const __attribute__((address_space(1))) void*)g,
      (__attribute__((address_space(3))) void*)l, 16, 0, 0);
}
#define SWZ(row) (((((row) & 3) | ((((row) >> 3) & 1) << 2)) << 4))

// ------- fused weight transpose+cast: all 8 weight mats in one grid ---------
__global__ __launch_bounds__(256) void wcast_all(
    const float* __restrict__ s0, const float* __restrict__ s1,
    const float* __restrict__ s2, const float* __restrict__ s3,
    const float* __restrict__ s4, const float* __restrict__ s5,
    const float* __restrict__ s6, const float* __restrict__ s7,
    u16* __restrict__ d0, u16* __restrict__ d1, u16* __restrict__ d2,
    u16* __restrict__ d3, u16* __restrict__ d4, u16* __restrict__ d5,
    u16* __restrict__ d6, u16* __restrict__ d7) {
  const int b = blockIdx.x;
  const float* W; u16* Wt; int K, N, lb;
  if (b < 768)       { W = s0; Wt = d0; K = 1024; N = 3072; lb = b; }
  else if (b < 1536) { W = s1; Wt = d1; K = 1024; N = 3072; lb = b - 768; }
  else if (b < 1792) { W = s2; Wt = d2; K = 1024; N = 1024; lb = b - 1536; }
  else if (b < 2048) { W = s3; Wt = d3; K = 1024; N = 1024; lb = b - 1792; }
  else if (b < 3072) { W = s4; Wt = d4; K = 1024; N = 4096; lb = b - 2048; }
  else if (b < 4096) { W = s5; Wt = d5; K = 1024; N = 4096; lb = b - 3072; }
  else if (b < 5120) { W = s6; Wt = d6; K = 4096; N = 1024; lb = b - 4096; }
  else               { W = s7; Wt = d7; K = 4096; N = 1024; lb = b - 5120; }
  const int ntn = N >> 6;
  const int n0 = (lb % ntn) * 64, k0 = (lb / ntn) * 64;
  __shared__ float T[64][65];
  const int tx = threadIdx.x & 15, ty = threadIdx.x >> 4;
#pragma unroll
  for (int i = 0; i < 4; ++i) {
    const int r = ty + i * 16;
    const float4 v = *(const float4*)&W[(size_t)(k0 + r) * N + n0 + tx * 4];
    T[r][tx * 4 + 0] = v.x;
    T[r][tx * 4 + 1] = v.y;
    T[r][tx * 4 + 2] = v.z;
    T[r][tx * 4 + 3] = v.w;
  }
  __syncthreads();
  const int rn = threadIdx.x >> 2;
  const int cs = (threadIdx.x & 3) * 16;
  u16 buf[16];
#pragma unroll
  for (int j = 0; j < 16; ++j) buf[j] = f2bf(T[cs + j][rn]);
  u16* dst = &Wt[(size_t)(n0 + rn) * K + k0 + cs];
  *(uint4*)dst = *(uint4*)&buf[0];
  *(uint4*)(dst + 8) = *(uint4*)&buf[8];
}

// ---------------- mod GEMV split-K ------------------------------------------
__global__ __launch_bounds__(256) void mod_gemv_part(
    const float* __restrict__ vec, const float* __restrict__ wi,
    const float* __restrict__ wt, float* __restrict__ part) {
  __shared__ float sv[128];
  const int s = blockIdx.y, kc = blockIdx.z;
  const float* W = s ? wt : wi;
  if (threadIdx.x < 128) {
    float x = vec[kc * 128 + threadIdx.x];
    sv[threadIdx.x] = x / (1.f + __expf(-x));
  }
  __syncthreads();
  const int j = blockIdx.x * 256 + threadIdx.x;
  float acc = 0.f;
#pragma unroll 4
  for (int i = 0; i < 128; ++i)
    acc += sv[i] * W[(size_t)(kc * 128 + i) * 6144 + j];
  part[((size_t)(kc * 2 + s)) * 6144 + j] = acc;
}
__global__ __launch_bounds__(256) void mod_reduce(
    const float* __restrict__ part, const float* __restrict__ bi,
    const float* __restrict__ bt, float* __restrict__ modout) {
  const int idx = blockIdx.x * 256 + threadIdx.x;
  const int s = idx / 6144, j = idx % 6144;
  float a = s ? bt[j] : bi[j];
#pragma unroll
  for (int kc = 0; kc < 8; ++kc) a += part[((size_t)(kc * 2 + s)) * 6144 + j];
  modout[(size_t)s * 6144 + j] = a;
}

// ---------------- fused LN1 + modulate (txt+img, float4) --------------------
__global__ __launch_bounds__(256) void ln_mod2(
    const float* __restrict__ Xtxt, const float* __restrict__ Ximg,
    u16* __restrict__ out, const float* __restrict__ tns,
    const float* __restrict__ tnb, const float* __restrict__ ins,
    const float* __restrict__ inb, const float* __restrict__ modv) {
  __shared__ float red[8];
  const int r = blockIdx.x, tid = threadIdx.x;
  const float* x; const float* ns; const float* nb; const float* mv;
  if (r < LTXT) { x = Xtxt + (size_t)r * DD; ns = tns; nb = tnb; mv = modv + 6144; }
  else { x = Ximg + (size_t)(r - LTXT) * DD; ns = ins; nb = inb; mv = modv; }
  const int c0 = tid * 4;
  const float4 xv = *(const float4*)&x[c0];
  float v[4] = {xv.x, xv.y, xv.z, xv.w};
  float s = 0.f, sq = 0.f;
#pragma unroll
  for (int i = 0; i < 4; ++i) { s += v[i]; sq += v[i] * v[i]; }
#pragma unroll
  for (int o = 32; o; o >>= 1) {
    s += __shfl_xor(s, o);
    sq += __shfl_xor(sq, o);
  }
  if ((tid & 63) == 0) {
    red[tid >> 6] = s;
    red[4 + (tid >> 6)] = sq;
  }
  __syncthreads();
  s = red[0] + red[1] + red[2] + red[3];
  sq = red[4] + red[5] + red[6] + red[7];
  const float mu = s * (1.f / DD);
  const float var = sq * (1.f / DD) - mu * mu;
  const float rstd = rsqrtf(var + 1e-6f);
  const float4 nsv = *(const float4*)&ns[c0];
  const float4 nbv = *(const float4*)&nb[c0];
  const float4 shv = *(const float4*)&mv[c0];
  const float4 scv = *(const float4*)&mv[1024 + c0];
  const float nsa[4] = {nsv.x, nsv.y, nsv.z, nsv.w};
  const float nba[4] = {nbv.x, nbv.y, nbv.z, nbv.w};
  const float sha[4] = {shv.x, shv.y, shv.z, shv.w};
  const float sca[4] = {scv.x, scv.y, scv.z, scv.w};
  ushort4 o4;
  u16 ob[4];
#pragma unroll
  for (int i = 0; i < 4; ++i) {
    const float ln = (v[i] - mu) * rstd * nsa[i] + nba[i];
    ob[i] = f2bf((1.f + sca[i]) * ln + sha[i]);
  }
  o4.x = ob[0]; o4.y = ob[1]; o4.z = ob[2]; o4.w = ob[3];
  *(ushort4*)&out[(size_t)r * DD + c0] = o4;
}

// ------- fused residual1 + LN2 + modulate (txt+img, float4) -----------------
__global__ __launch_bounds__(256) void resid_ln2(
    const float* __restrict__ Xtxt, const float* __restrict__ Ximg,
    const u16* __restrict__ t, const float* __restrict__ modv,
    const float* __restrict__ tns, const float* __restrict__ tnb,
    const float* __restrict__ ins, const float* __restrict__ inb,
    float* __restrict__ otxt, float* __restrict__ oimg,
    u16* __restrict__ hout) {
  __shared__ float red[8];
  const int r = blockIdx.x, tid = threadIdx.x;
  const float* x; const float* ns; const float* nb; const float* mv; float* y;
  if (r < LTXT) {
    x = Xtxt + (size_t)r * DD; ns = tns; nb = tnb; mv = modv + 6144;
    y = otxt + (size_t)r * DD;
  } else {
    x = Ximg + (size_t)(r - LTXT) * DD; ns = ins; nb = inb; mv = modv;
    y = oimg + (size_t)(r - LTXT) * DD;
  }
  const int c0 = tid * 4;
  const float4 xv = *(const float4*)&x[c0];
  const ushort4 tb = *(const ushort4*)&t[(size_t)r * DD + c0];
  const float4 gv = *(const float4*)&mv[2048 + c0];
  float v[4];
  v[0] = xv.x + gv.x * bf2f(tb.x);
  v[1] = xv.y + gv.y * bf2f(tb.y);
  v[2] = xv.z + gv.z * bf2f(tb.z);
  v[3] = xv.w + gv.w * bf2f(tb.w);
  *(float4*)&y[c0] = *(float4*)v;
  float s = 0.f, sq = 0.f;
#pragma unroll
  for (int i = 0; i < 4; ++i) { s += v[i]; sq += v[i] * v[i]; }
#pragma unroll
  for (int o = 32; o; o >>= 1) {
    s += __shfl_xor(s, o);
    sq += __shfl_xor(sq, o);
  }
  if ((tid & 63) == 0) {
    red[tid >> 6] = s;
    red[4 + (tid >> 6)] = sq;
  }
  __syncthreads();
  s = red[0] + red[1] + red[2] + red[3];
  sq = red[4] + red[5] + red[6] + red[7];
  const float mu = s * (1.f / DD);
  const float var = sq * (1.f / DD) - mu * mu;
  const float rstd = rsqrtf(var + 1e-6f);
  const float4 nsv = *(const float4*)&ns[c0];
  const float4 nbv = *(const float4*)&nb[c0];
  const float4 shv = *(const float4*)&mv[3072 + c0];
  const float4 scv = *(const float4*)&mv[4096 + c0];
  const float nsa[4] = {nsv.x, nsv.y, nsv.z, nsv.w};
  const float nba[4] = {nbv.x, nbv.y, nbv.z, nbv.w};
  const float sha[4] = {shv.x, shv.y, shv.z, shv.w};
  const float sca[4] = {scv.x, scv.y, scv.z, scv.w};
  ushort4 o4;
  u16 ob[4];
#pragma unroll
  for (int i = 0; i < 4; ++i) {
    const float ln = (v[i] - mu) * rstd * nsa[i] + nba[i];
    ob[i] = f2bf((1.f + sca[i]) * ln + sha[i]);
  }
  o4.x = ob[0]; o4.y = ob[1]; o4.z = ob[2]; o4.w = ob[3];
  *(ushort4*)&hout[(size_t)r * DD + c0] = o4;
}

// --- bf16 MFMA GEMM, 128x128, BK=32, 8 waves (4x2 of 32x64), 2-buf 2-barrier
__global__ __launch_bounds__(512) void gemm_pipe(
    const u16* __restrict__ A, const u16* __restrict__ BtT,
    const u16* __restrict__ BtI, const float* __restrict__ biasT,
    const float* __restrict__ biasI, u16* __restrict__ C,
    float* __restrict__ Cpart, int K, int Kblk, int N, int gelu) {
  __shared__ __align__(16) u16 As[2][128 * 32];
  __shared__ __align__(16) u16 Bs[2][128 * 32];
  const int tid = threadIdx.x, lane = tid & 63, wave = tid >> 6;  // 0..7
  const int nwg = gridDim.x * gridDim.y;
  const int orig = blockIdx.x + blockIdx.y * gridDim.x;
  const int lb = (orig & 7) * (nwg >> 3) + (orig >> 3);
  const int bn = lb / 20, bm = lb % 20;
  const int kc = blockIdx.z;
  const u16* Bt = (bm < (LTXT / 128)) ? BtT : BtI;
  const int wm = wave >> 1, wn = wave & 1;  // 4 x 2 wave grid
  const int lr = lane & 15, lk = lane >> 4;
  f32x4 acc[2][4] = {};
  const size_t a0 = (size_t)bm * 128;
  const size_t b0 = (size_t)bn * 128;
  const int kbase = kc * Kblk;
  const int NT = Kblk >> 5;
  const int srow = tid >> 2, soff = (tid & 3) * 8;  // 128 rows x 4 chunks

#define STAGE(t, buf)                                                         \
  {                                                                           \
    const int k0_ = kbase + (t) * 32;                                         \
    gload16(&A[(a0 + srow) * K + k0_ + soff], &As[buf][srow * 32 + soff]);    \
    gload16(&Bt[(b0 + srow) * K + k0_ + soff], &Bs[buf][srow * 32 + soff]);   \
  }

  STAGE(0, 0);
  STAGE(1, 1);
  for (int t = 0; t < NT; ++t) {
    if (t + 1 < NT) {
      asm volatile("s_waitcnt vmcnt(2)" ::: "memory");
    } else {
      asm volatile("s_waitcnt vmcnt(0)" ::: "memory");
    }
    __builtin_amdgcn_s_barrier();
    const int b = t & 1;
    bf16x8 af[2], bfv[4];
#pragma unroll
    for (int m = 0; m < 2; ++m)
      af[m] = *(const bf16x8*)&As[b][(wm * 32 + m * 16 + lr) * 32 + lk * 8];
#pragma unroll
    for (int n = 0; n < 4; ++n)
      bfv[n] = *(const bf16x8*)&Bs[b][(wn * 64 + n * 16 + lr) * 32 + lk * 8];
    asm volatile("s_waitcnt lgkmcnt(0)" ::: "memory");
    __builtin_amdgcn_sched_barrier(0);
    __builtin_amdgcn_s_barrier();
    if (t + 2 < NT) STAGE(t + 2, b);
    __builtin_amdgcn_sched_barrier(0);
    __builtin_amdgcn_s_setprio(1);
#pragma unroll
    for (int m = 0; m < 2; ++m)
#pragma unroll
      for (int n = 0; n < 4; ++n)
        acc[m][n] = __builtin_amdgcn_mfma_f32_16x16x32_bf16(af[m], bfv[n],
                                                            acc[m][n], 0, 0, 0);
    __builtin_amdgcn_s_setprio(0);
  }
#undef STAGE

  if (Cpart) {
    float* dst = Cpart + (size_t)kc * ((size_t)LTOT * N);
#pragma unroll
    for (int n = 0; n < 4; ++n) {
      const int col = bn * 128 + wn * 64 + n * 16 + lr;
#pragma unroll
      for (int m = 0; m < 2; ++m)
#pragma unroll
        for (int r = 0; r < 4; ++r) {
          const size_t row = a0 + wm * 32 + m * 16 + lk * 4 + r;
          dst[row * (size_t)N + col] = acc[m][n][r];
        }
    }
  } else {
    const float* bias = (bm < (LTXT / 128)) ? biasT : biasI;
#pragma unroll
    for (int n = 0; n < 4; ++n) {
      const int col = bn * 128 + wn * 64 + n * 16 + lr;
      const float bv = bias[col];
#pragma unroll
      for (int m = 0; m < 2; ++m)
#pragma unroll
        for (int r = 0; r < 4; ++r) {
          const size_t row = a0 + wm * 32 + m * 16 + lk * 4 + r;
          float v = acc[m][n][r] + bv;
          if (gelu) v = geluf(v);
          C[row * (size_t)N + col] = f2bf(v);
        }
    }
  }
}

// ---------------- split-K reduce: C = bf16(sum(part) + bias) ----------------
__global__ __launch_bounds__(256) void gemm_reduce(
    const float* __restrict__ part, const float* __restrict__ bT,
    const float* __restrict__ bI, u16* __restrict__ C, int N, int kcnt) {
  const size_t idx = (size_t)(blockIdx.x * 256 + threadIdx.x) * 4;
  const int row = (int)(idx / N), col = (int)(idx % N);
  float4 a = *(const float4*)&part[idx];
  for (int kc = 1; kc < kcnt; ++kc) {
    const float4 b = *(const float4*)&part[(size_t)kc * LTOT * N + idx];
    a.x += b.x; a.y += b.y; a.z += b.z; a.w += b.w;
  }
  const float* bias = (row < LTXT) ? bT : bI;
  ushort4 o;
  o.x = f2bf(a.x + bias[col]);
  o.y = f2bf(a.y + bias[col + 1]);
  o.z = f2bf(a.z + bias[col + 2]);
  o.w = f2bf(a.w + bias[col + 3]);
  *(ushort4*)&C[idx] = o;
}

// ------- MLP2 split-K reduce + bias + gated residual2 into d_out ------------
__global__ __launch_bounds__(256) void gemm_reduce_gate(
    const float* __restrict__ part, const float* __restrict__ bT,
    const float* __restrict__ bI, const float* __restrict__ modv,
    float* __restrict__ otxt, float* __restrict__ oimg, int kcnt) {
  const size_t idx = (size_t)(blockIdx.x * 256 + threadIdx.x) * 4;
  const int row = (int)(idx >> 10), col = (int)(idx & 1023);
  float4 a = *(const float4*)&part[idx];
  for (int kc = 1; kc < kcnt; ++kc) {
    const float4 b = *(const float4*)&part[(size_t)kc * LTOT * DD + idx];
    a.x += b.x; a.y += b.y; a.z += b.z; a.w += b.w;
  }
  const float* bias; const float* mv; float* o;
  if (row < LTXT) {
    bias = bT; mv = modv + 6144; o = otxt + (size_t)row * DD + col;
  } else {
    bias = bI; mv = modv; o = oimg + (size_t)(row - LTXT) * DD + col;
  }
  const float4 g = *(const float4*)&mv[5120 + col];
  const float4 cur = *(const float4*)o;
  float4 r;
  r.x = cur.x + g.x * (a.x + bias[col]);
  r.y = cur.y + g.y * (a.y + bias[col + 1]);
  r.z = cur.z + g.z * (a.z + bias[col + 2]);
  r.w = cur.w + g.w * (a.w + bias[col + 3]);
  *(float4*)o = r;
}

// ------- fused scatter + RMS + RoPE for q,k (wave per (h,l)) ----------------
// q is pre-scaled by 0.125*log2(e) so attention softmax runs in exp2 domain.
__global__ __launch_bounds__(256) void scat_rope(
    const u16* __restrict__ qkv, u16* __restrict__ q, u16* __restrict__ k,
    const float* __restrict__ pe, const float* __restrict__ iqs,
    const float* __restrict__ iks, const float* __restrict__ tqs,
    const float* __restrict__ tks) {
  const int gw = (blockIdx.x * 256 + threadIdx.x) >> 6;
  const int lane = threadIdx.x & 63;
  const int l = gw % LTOT, h = gw / LTOT;
  const size_t rb = (size_t)l * 3072 + h * 64 + lane;
  const float qv = bf2f(qkv[rb]);
  const float kv = bf2f(qkv[rb + 1024]);
  const float* qs = (l < LTXT) ? tqs : iqs;
  const float* ks = (l < LTXT) ? tks : iks;
  const float* peb = pe + (size_t)l * 128 + (lane >> 1) * 4 + (lane & 1) * 2;
  const size_t base = ((size_t)h * LTOT + l) * HD + lane;
  {
    float ss = qv * qv;
#pragma unroll
    for (int o = 32; o; o >>= 1) ss += __shfl_xor(ss, o);
    float xn = qv * rsqrtf(ss * (1.f / HD) + 1e-6f) * qs[lane];
    float part = __shfl_xor(xn, 1);
    float x0 = (lane & 1) ? part : xn;
    float x1 = (lane & 1) ? xn : part;
    q[base] = f2bf((peb[0] * x0 + peb[1] * x1) * 0.1803368801111f);
  }
  {
    float ss = kv * kv;
#pragma unroll
    for (int o = 32; o; o >>= 1) ss += __shfl_xor(ss, o);
    float xn = kv * rsqrtf(ss * (1.f / HD) + 1e-6f) * ks[lane];
    float part = __shfl_xor(xn, 1);
    float x0 = (lane & 1) ? part : xn;
    float x1 = (lane & 1) ? xn : part;
    k[base] = f2bf(peb[0] * x0 + peb[1] * x1);
  }
}

// ------- V transpose via LDS: qkv (L,3072) col-block -> VT (H,64,L) ---------
__global__ __launch_bounds__(256) void vt_build(const u16* __restrict__ qkv,
                                                u16* __restrict__ vt) {
  __shared__ u16 T[64][72];
  const int b = blockIdx.x;
  const int h = b & 15, lt = b >> 4;
  const int tid = threadIdx.x;
  const int r = tid >> 3, c8 = (tid & 7) * 8;
  const size_t srcbase = (size_t)(lt * 64) * 3072 + 2048 + h * 64;
  *(uint4*)&T[r][c8] = *(const uint4*)&qkv[srcbase + (size_t)r * 3072 + c8];
  *(uint4*)&T[r + 32][c8] =
      *(const uint4*)&qkv[srcbase + (size_t)(r + 32) * 3072 + c8];
  __syncthreads();
  const int d = tid >> 2, lc = (tid & 3) * 16;
  u16 buf[16];
#pragma unroll
  for (int j = 0; j < 16; ++j) buf[j] = T[lc + j][d];
  u16* dst = &vt[((size_t)h * 64 + d) * LTOT + lt * 64 + lc];
  *(uint4*)dst = *(uint4*)&buf[0];
  *(uint4*)(dst + 8) = *(uint4*)&buf[8];
}

// ---- MFMA flash attention: 8 waves x 16q, 128 q/block, split-KV {1,2,4} ----
// exp2-domain softmax (Q pre-scaled). l computed via ones-row MFMA in the PV
// cluster (replaces 16 fma + 2 shfl on the VALU pipe). Partials: 64 bf16 +
// f32 m,l per (q,h) in stride-80 u16 rows.
template <int SPLIT>
__global__ __launch_bounds__(512) void attn_mfma(
    const u16* __restrict__ Q, const u16* __restrict__ Kg,
    const u16* __restrict__ VT, u16* __restrict__ out,
    u16* __restrict__ part) {
  constexpr int LOG = (SPLIT == 4) ? 2 : ((SPLIT == 2) ? 1 : 0);
  __shared__ __align__(16) u16 Ks[2][64 * 64];
  __shared__ __align__(16) u16 Vs[2][64 * 64];
  const int tid = threadIdx.x, lane = tid & 63, w = tid >> 6;  // w = 0..7
  const int lr = lane & 15, lk = lane >> 4;
  const int blk = blockIdx.x;
  const int h = ((blk & 7) << 1) | ((blk >> 3) & 1);
  const int half = (blk >> 4) & (SPLIT - 1);
  const int q0 = (blk >> (4 + LOG)) * 128;
  const size_t hb = (size_t)h * LTOT;
  char* KsB0 = (char*)&Ks[0][0];
  char* VsB0 = (char*)&Vs[0][0];

  union { u16 u[8]; bf16x8 v; } one8;
#pragma unroll
  for (int i = 0; i < 8; ++i) one8.u[i] = 0x3F80;  // bf16 1.0

  const int q = q0 + w * 16 + lr;
  const bf16x8 qa0 = *(const bf16x8*)&Q[(hb + q) * HD + lk * 8];
  const bf16x8 qa1 = *(const bf16x8*)&Q[(hb + q) * HD + 32 + lk * 8];

  const int srow = tid >> 3;  // 0..63
  const int soff = tid & 7;
  const int NT = (LTOT / SPLIT) / 64;
  const int kstart = half * (LTOT / SPLIT);

  float m_run = -1e30f;
  f32x4 acc[4] = {};
  f32x4 accL = {};  // ones-row MFMA accumulator; [0] == running l
  uint4 kst, vst;

  kst = *(const uint4*)&Kg[(hb + kstart + srow) * HD + soff * 8];
  vst = *(const uint4*)&VT[((size_t)h * HD + srow) * LTOT + kstart + soff * 8];
  *(uint4*)(KsB0 + ((srow * 128 + soff * 16) ^ SWZ(srow))) = kst;
  *(uint4*)(VsB0 + ((srow * 128 + soff * 16) ^ SWZ(srow))) = vst;
  __syncthreads();

  for (int t = 0; t < NT; ++t) {
    char* KsC = KsB0 + (t & 1) * 8192;
    char* VsC = VsB0 + (t & 1) * 8192;
    if (t + 1 < NT) {
      const int k0n = kstart + (t + 1) * 64;
      kst = *(const uint4*)&Kg[(hb + k0n + srow) * HD + soff * 8];
      vst = *(const uint4*)&VT[((size_t)h * HD + srow) * LTOT + k0n + soff * 8];
    }
    f32x4 s[4];
    __builtin_amdgcn_s_setprio(1);
#pragma unroll
    for (int g = 0; g < 4; ++g) {
      const int kr = (lr >> 2) * 8 + (g & 1) * 4 + (lr & 3) + (g >> 1) * 32;
      const int sw = SWZ(kr);
      const bf16x8 ka0 = *(const bf16x8*)(KsC + ((kr * 128 + lk * 16) ^ sw));
      const bf16x8 ka1 = *(const bf16x8*)(KsC + ((kr * 128 + 64 + lk * 16) ^ sw));
      f32x4 z = {0.f, 0.f, 0.f, 0.f};
      z = __builtin_amdgcn_mfma_f32_16x16x32_bf16(ka0, qa0, z, 0, 0, 0);
      z = __builtin_amdgcn_mfma_f32_16x16x32_bf16(ka1, qa1, z, 0, 0, 0);
      s[g] = z;
    }
    __builtin_amdgcn_s_setprio(0);
    // tree max (depth 4); scores already in log2 units
    float gm[4];
#pragma unroll
    for (int g = 0; g < 4; ++g)
      gm[g] = fmaxf(fmaxf(s[g][0], s[g][1]), fmaxf(s[g][2], s[g][3]));
    float tmax = fmaxf(fmaxf(gm[0], gm[1]), fmaxf(gm[2], gm[3]));
    tmax = fmaxf(tmax, __shfl_xor(tmax, 16));
    tmax = fmaxf(tmax, __shfl_xor(tmax, 32));
    if (!__all(tmax <= m_run + 11.5415603f)) {  // 8 nats in log2
      const float mnew = fmaxf(m_run, tmax);
      const float alpha = fexp2(m_run - mnew);
#pragma unroll
      for (int dt = 0; dt < 4; ++dt) {
        acc[dt][0] *= alpha;
        acc[dt][1] *= alpha;
        acc[dt][2] *= alpha;
        acc[dt][3] *= alpha;
      }
      accL[0] *= alpha;
      accL[1] *= alpha;
      accL[2] *= alpha;
      accL[3] *= alpha;
      m_run = mnew;
    }
    float p[4][4];
#pragma unroll
    for (int g = 0; g < 4; ++g)
#pragma unroll
      for (int r = 0; r < 4; ++r) p[g][r] = fexp2(s[g][r] - m_run);
    union { uint32_t u[4]; bf16x8 v; } pb0, pb1;
    pb0.u[0] = cvtpk(p[0][0], p[0][1]);
    pb0.u[1] = cvtpk(p[0][2], p[0][3]);
    pb0.u[2] = cvtpk(p[1][0], p[1][1]);
    pb0.u[3] = cvtpk(p[1][2], p[1][3]);
    pb1.u[0] = cvtpk(p[2][0], p[2][1]);
    pb1.u[1] = cvtpk(p[2][2], p[2][3]);
    pb1.u[2] = cvtpk(p[3][0], p[3][1]);
    pb1.u[3] = cvtpk(p[3][2], p[3][3]);
    __builtin_amdgcn_s_setprio(1);
    // l via ones-row: accL[i][q] += sum_k P[k][q] (all rows identical)
    accL = __builtin_amdgcn_mfma_f32_16x16x32_bf16(one8.v, pb0.v, accL, 0, 0, 0);
    accL = __builtin_amdgcn_mfma_f32_16x16x32_bf16(one8.v, pb1.v, accL, 0, 0, 0);
#pragma unroll
    for (int dt = 0; dt < 4; ++dt) {
      const int vr = dt * 16 + lr;
      const int sw = SWZ(vr);
      const bf16x8 va0 = *(const bf16x8*)(VsC + ((vr * 128 + lk * 16) ^ sw));
      const bf16x8 va1 = *(const bf16x8*)(VsC + ((vr * 128 + 64 + lk * 16) ^ sw));
      acc[dt] = __builtin_amdgcn_mfma_f32_16x16x32_bf16(va0, pb0.v, acc[dt], 0, 0, 0);
      acc[dt] = __builtin_amdgcn_mfma_f32_16x16x32_bf16(va1, pb1.v, acc[dt], 0, 0, 0);
    }
    __builtin_amdgcn_s_setprio(0);
    if (t + 1 < NT) {
      char* KsN = KsB0 + ((t + 1) & 1) * 8192;
      char* VsN = VsB0 + ((t + 1) & 1) * 8192;
      *(uint4*)(KsN + ((srow * 128 + soff * 16) ^ SWZ(srow))) = kst;
      *(uint4*)(VsN + ((srow * 128 + soff * 16) ^ SWZ(srow))) = vst;
      __syncthreads();
    }
  }
  const float l_run = accL[0];
  if (SPLIT > 1) {
    u16* pr = part + (((size_t)(half * LTOT) + q) * 16 + h) * 80;
#pragma unroll
    for (int dt = 0; dt < 4; ++dt) {
      uint2 o;
      o.x = cvtpk(acc[dt][0], acc[dt][1]);
      o.y = cvtpk(acc[dt][2], acc[dt][3]);
      *(uint2*)&pr[dt * 16 + lk * 4] = o;
    }
    if (lk == 0) {
      *(float*)&pr[64] = m_run;
      *(float*)&pr[66] = l_run;
    }
  } else {
    __syncthreads();
    const float inv = 1.f / l_run;
    char* ob = KsB0 + w * 2048;
    const int esw = (lr & 7) << 4;
#pragma unroll
    for (int dt = 0; dt < 4; ++dt) {
      const uint32_t a = cvtpk(acc[dt][0] * inv, acc[dt][1] * inv);
      const uint32_t b2 = cvtpk(acc[dt][2] * inv, acc[dt][3] * inv);
      const int ad = lr * 128 + dt * 32 + lk * 8;
      *(uint32_t*)(ob + (ad ^ esw)) = a;
      *(uint32_t*)(ob + ((ad + 4) ^ esw)) = b2;
    }
    __syncthreads();
    const int row = lane >> 2, ch = lane & 3;
    const int rsw = (row & 7) << 4;
    const uint4 o0 = *(const uint4*)(ob + ((row * 128 + ch * 32) ^ rsw));
    const uint4 o1 = *(const uint4*)(ob + ((row * 128 + ch * 32 + 16) ^ rsw));
    u16* orow = &out[(size_t)(q0 + w * 16 + row) * DD + h * HD + ch * 16];
    *(uint4*)orow = o0;
    *(uint4*)(orow + 8) = o1;
  }
}

// ---------------- merge SPLIT KV parts (bf16) -> bf16 out (L,1024) ----------
template <int SPLIT>
__global__ __launch_bounds__(256) void attn_merge(const u16* __restrict__ part,
                                                  u16* __restrict__ out) {
  const int idx = blockIdx.x * 256 + threadIdx.x;
  const int d4 = idx & 15, h = (idx >> 4) & 15, q = idx >> 8;
  const u16* bp[SPLIT];
  float ms[SPLIT], ls[SPLIT];
  float m = -1e30f;
#pragma unroll
  for (int s = 0; s < SPLIT; ++s) {
    bp[s] = part + (((size_t)(s * LTOT) + q) * 16 + h) * 80;
    ms[s] = *(const float*)&bp[s][64];
    ls[s] = *(const float*)&bp[s][66];
    m = fmaxf(m, ms[s]);
  }
  float denom = 0.f;
  float a[SPLIT];
#pragma unroll
  for (int s = 0; s < SPLIT; ++s) {
    a[s] = fexp2(ms[s] - m);
    denom += ls[s] * a[s];
  }
  const float inv = 1.f / denom;
  float r[4] = {0.f, 0.f, 0.f, 0.f};
#pragma unroll
  for (int s = 0; s < SPLIT; ++s) {
    const uint2 xr = *(const uint2*)&bp[s][d4 * 4];
    const u16* xp = (const u16*)&xr;
    const float sc = a[s] * inv;
    r[0] += bf2f(xp[0]) * sc;
    r[1] += bf2f(xp[1]) * sc;
    r[2] += bf2f(xp[2]) * sc;
    r[3] += bf2f(xp[3]) * sc;
  }
  uint2 o;
  o.x = cvtpk(r[0], r[1]);
  o.y = cvtpk(r[2], r[3]);
  *(uint2*)&out[(size_t)q * DD + h * HD + d4 * 4] = o;
}

// ---------------- gated residual (fallback path only) -----------------------
__global__ __launch_bounds__(256) void resid_gate(
    const float* __restrict__ xin, const u16* __restrict__ t,
    const float* __restrict__ g, float* __restrict__ out, int n4) {
  const int idx = blockIdx.x * 256 + threadIdx.x;
  if (idx >= n4) return;
  const int col = (idx * 4) & (DD - 1);
  const float4 a = ((const float4*)xin)[idx];
  const ushort4 tb = ((const ushort4*)t)[idx];
  const float4 gg = *(const float4*)&g[col];
  float4 r;
  r.x = a.x + gg.x * bf2f(tb.x);
  r.y = a.y + gg.y * bf2f(tb.y);
  r.z = a.z + gg.z * bf2f(tb.z);
  r.w = a.w + gg.w * bf2f(tb.w);
  ((float4*)out)[idx] = r;
}

extern "C" void kernel_launch(void* const* d_in, const int* in_sizes, int n_in,
                              void* d_out, int out_size, void* d_ws,
                              size_t ws_size, hipStream_t stream) {
  const float* img = (const float*)d_in[0];
  const float* txt = (const float*)d_in[1];
  const float* vec = (const float*)d_in[2];
  const float* pe = (const float*)d_in[3];
  const float* i_mod_w = (const float*)d_in[4];
  const float* i_mod_b = (const float*)d_in[5];
  const float* i_n1s = (const float*)d_in[6];
  const float* i_n1b = (const float*)d_in[7];
  const float* i_qkv_w = (const float*)d_in[8];
  const float* i_qkv_b = (const float*)d_in[9];
  const float* i_qs = (const float*)d_in[10];
  const float* i_ks = (const float*)d_in[11];
  const float* i_proj_w = (const float*)d_in[12];
  const float* i_proj_b = (const float*)d_in[13];
  const float* i_n2s = (const float*)d_in[14];
  const float* i_n2b = (const float*)d_in[15];
  const float* i_w1 = (const float*)d_in[16];
  const float* i_b1 = (const float*)d_in[17];
  const float* i_w2 = (const float*)d_in[18];
  const float* i_b2 = (const float*)d_in[19];
  const float* t_mod_w = (const float*)d_in[20];
  const float* t_mod_b = (const float*)d_in[21];
  const float* t_n1s = (const float*)d_in[22];
  const float* t_n1b = (const float*)d_in[23];
  const float* t_qkv_w = (const float*)d_in[24];
  const float* t_qkv_b = (const float*)d_in[25];
  const float* t_qs = (const float*)d_in[26];
  const float* t_ks = (const float*)d_in[27];
  const float* t_proj_w = (const float*)d_in[28];
  const float* t_proj_b = (const float*)d_in[29];
  const float* t_n2s = (const float*)d_in[30];
  const float* t_n2b = (const float*)d_in[31];
  const float* t_w1 = (const float*)d_in[32];
  const float* t_b1 = (const float*)d_in[33];
  const float* t_w2 = (const float*)d_in[34];
  const float* t_b2 = (const float*)d_in[35];

  const size_t LD = (size_t)LTOT * DD;
  uint8_t* p = (uint8_t*)d_ws;
  float* modb = (float*)p;           p += 64 * 1024;
  float* part = (float*)p;           p += 512 * 1024;
  u16* tqkvT = (u16*)p;              p += (size_t)3072 * 1024 * 2;
  u16* iqkvT = (u16*)p;              p += (size_t)3072 * 1024 * 2;
  u16* tprojT = (u16*)p;             p += (size_t)1024 * 1024 * 2;
  u16* iprojT = (u16*)p;             p += (size_t)1024 * 1024 * 2;
  u16* tw1T = (u16*)p;               p += (size_t)4096 * 1024 * 2;
  u16* iw1T = (u16*)p;               p += (size_t)4096 * 1024 * 2;
  u16* tw2T = (u16*)p;               p += (size_t)1024 * 4096 * 2;
  u16* iw2T = (u16*)p;               p += (size_t)1024 * 4096 * 2;
  u16* actA = (u16*)p;               p += LD * 2;
  u16* actB = (u16*)p;               p += (size_t)LTOT * DMLP * 2;
  u16* actC = (u16*)p;               p += LD * 2 * 3;
  float* gpart = (float*)p;
  const size_t used = (size_t)(p - (uint8_t*)d_ws);
  const size_t avail = ws_size > used ? ws_size - used : 0;
  const size_t attn_need2 = (size_t)2 * LTOT * 16 * 80 * sizeof(u16);
  const size_t attn_need4 = 2 * attn_need2;
  const int attn_split = avail >= attn_need4 ? 4 : (avail >= attn_need2 ? 2 : 1);
  const int kc_proj = avail >= 2 * LD * sizeof(float) ? 2 : 1;
  const int kc_mlp2 = avail >= 4 * LD * sizeof(float)
                          ? 4
                          : (avail >= 2 * LD * sizeof(float) ? 2 : 1);
  float* out_img = (float*)d_out;
  float* out_txt = out_img + (size_t)LIMG * DD;

  // 0. weight transpose+cast
  wcast_all<<<6144, 256, 0, stream>>>(t_qkv_w, i_qkv_w, t_proj_w, i_proj_w,
                                      t_w1, i_w1, t_w2, i_w2, tqkvT, iqkvT,
                                      tprojT, iprojT, tw1T, iw1T, tw2T, iw2T);
  // 1. modulation
  mod_gemv_part<<<dim3(24, 2, 8), 256, 0, stream>>>(vec, i_mod_w, t_mod_w, part);
  mod_reduce<<<48, 256, 0, stream>>>(part, i_mod_b, t_mod_b, modb);
  // 2. LN1+mod -> actA
  ln_mod2<<<LTOT, 256, 0, stream>>>(txt, img, actA, t_n1s, t_n1b, i_n1s, i_n1b,
                                    modb);
  // 3. QKV GEMM -> actB
  gemm_pipe<<<dim3(24, 20, 1), 512, 0, stream>>>(actA, tqkvT, iqkvT, t_qkv_b,
                                                 i_qkv_b, actB, nullptr, 1024,
                                                 1024, 3072, 0);
  // 4. q,k scatter + RMS + RoPE ; V transpose
  scat_rope<<<10240, 256, 0, stream>>>(actB, actC, actC + LD, pe, i_qs, i_ks,
                                       t_qs, t_ks);
  vt_build<<<640, 256, 0, stream>>>(actB, actC + 2 * LD);
  // 6. attention (8 waves x 16q, split-KV) -> actA
  if (attn_split == 4) {
    attn_mfma<4><<<1280, 512, 0, stream>>>(actC, actC + LD, actC + 2 * LD,
                                           actA, (u16*)gpart);
    attn_merge<4><<<2560, 256, 0, stream>>>((const u16*)gpart, actA);
  } else if (attn_split == 2) {
    attn_mfma<2><<<640, 512, 0, stream>>>(actC, actC + LD, actC + 2 * LD,
                                          actA, (u16*)gpart);
    attn_merge<2><<<2560, 256, 0, stream>>>((const u16*)gpart, actA);
  } else {
    attn_mfma<1><<<320, 512, 0, stream>>>(actC, actC + LD, actC + 2 * LD, actA,
                                          nullptr);
  }
  // 7. proj GEMM (split-K) -> actC
  if (kc_proj > 1) {
    gemm_pipe<<<dim3(8, 20, kc_proj), 512, 0, stream>>>(
        actA, tprojT, iprojT, nullptr, nullptr, nullptr, gpart, 1024,
        1024 / kc_proj, 1024, 0);
    gemm_reduce<<<2560, 256, 0, stream>>>(gpart, t_proj_b, i_proj_b, actC,
                                          1024, kc_proj);
  } else {
    gemm_pipe<<<dim3(8, 20, 1), 512, 0, stream>>>(actA, tprojT, iprojT,
                                                  t_proj_b, i_proj_b, actC,
                                                  nullptr, 1024, 1024, 1024, 0);
  }
  // 8+9. fused residual1 + LN2+mod
  resid_ln2<<<LTOT, 256, 0, stream>>>(txt, img, actC, modb, t_n2s, t_n2b,
                                      i_n2s, i_n2b, out_txt, out_img,
                                      actC + LD);
  // 10. MLP1+GELU -> actB
  gemm_pipe<<<dim3(32, 20, 1), 512, 0, stream>>>(actC + LD, tw1T, iw1T, t_b1,
                                                 i_b1, actB, nullptr, 1024,
                                                 1024, 4096, 1);
  // 11+12. MLP2 (split-K) + fused reduce+bias+gate residual2 -> d_out
  if (kc_mlp2 > 1) {
    gemm_pipe<<<dim3(8, 20, kc_mlp2), 512, 0, stream>>>(
        actB, tw2T, iw2T, nullptr, nullptr, nullptr, gpart, 4096,
        4096 / kc_mlp2, 1024, 0);
    gemm_reduce_gate<<<2560, 256, 0, stream>>>(gpart, t_b2, i_b2, modb,
                                               out_txt, out_img, kc_mlp2);
  } else {
    gemm_pipe<<<dim3(8, 20, 1), 512, 0, stream>>>(actB, tw2T, iw2T, t_b2, i_b2,
                                                  actC + 2 * LD, nullptr, 4096,
                                                  4096, 1024, 0);
    resid_gate<<<2048, 256, 0, stream>>>(out_img,
                                         actC + 2 * LD + (size_t)LTXT * DD,
                                         modb + 5120, out_img, LIMG * DD / 4);
    resid_gate<<<512, 256, 0, stream>>>(out_txt, actC + 2 * LD,
                                        modb + 6144 + 5120, out_txt,
                                        LTXT * DD / 4);
  }
}

// Round 19
// 243.872 us; speedup vs baseline: 1.0834x; 1.0510x over previous
//
#include <hip/hip_runtime.h>
#include <cstdint>
#include <cstddef>

#define DD 1024
#define HD 64
#define NH 16
#define LTXT 512
#define LIMG 2048
#define LTOT 2560
#define DMLP 4096

typedef unsigned short u16;
typedef __attribute__((ext_vector_type(8))) __bf16 bf16x8;
typedef __attribute__((ext_vector_type(4))) float f32x4;

__device__ __forceinline__ u16 f2bf(float f) {
  union { float f; uint32_t u; } v; v.f = f;
  uint32_t r = v.u + 0x7FFFu + ((v.u >> 16) & 1u);
  return (u16)(r >> 16);
}
__device__ __forceinline__ float bf2f(u16 u) {
  union { uint32_t u; float f; } v; v.u = ((uint32_t)u) << 16;
  return v.f;
}
__device__ __forceinline__ uint32_t cvtpk(float lo, float hi) {
  uint32_t r;
  asm("v_cvt_pk_bf16_f32 %0, %1, %2" : "=v"(r) : "v"(lo), "v"(hi));
  return r;
}
// native v_exp_f32 (2^x) — NOT libm exp2f (round-6 regression trap)
__device__ __forceinline__ float fexp2(float x) {
  return __builtin_amdgcn_exp2f(x);
}
// gelu via native sigmoid: 0.5x(1+tanh(z)) == x * sigmoid(2z)
__device__ __forceinline__ float geluf(float x) {
  const float u = fmaf(x * x, 0.044715f, 1.0f);
  const float e = __expf(x * u * -1.5957691216057308f);
  return x / (1.f + e);
}
__device__ __forceinline__ void gload16(const void* g, void* l) {
  __builtin_amdgcn_global_load_lds(
      (const __attribute__((address_space(1))) void*)g,
      (__attribute__((address_space(3))) void*)l, 16, 0, 0);
}
#define SWZ(row) (((((row) & 3) | ((((row) >> 3) & 1) << 2)) << 4))

// ------- fused weight transpose+cast: all 8 weight mats in one grid ---------
__global__ __launch_bounds__(256) void wcast_all(
    const float* __restrict__ s0, const float* __restrict__ s1,
    const float* __restrict__ s2, const float* __restrict__ s3,
    const float* __restrict__ s4, const float* __restrict__ s5,
    const float* __restrict__ s6, const float* __restrict__ s7,
    u16* __restrict__ d0, u16* __restrict__ d1, u16* __restrict__ d2,
    u16* __restrict__ d3, u16* __restrict__ d4, u16* __restrict__ d5,
    u16* __restrict__ d6, u16* __restrict__ d7) {
  const int b = blockIdx.x;
  const float* W; u16* Wt; int K, N, lb;
  if (b < 768)       { W = s0; Wt = d0; K = 1024; N = 3072; lb = b; }
  else if (b < 1536) { W = s1; Wt = d1; K = 1024; N = 3072; lb = b - 768; }
  else if (b < 1792) { W = s2; Wt = d2; K = 1024; N = 1024; lb = b - 1536; }
  else if (b < 2048) { W = s3; Wt = d3; K = 1024; N = 1024; lb = b - 1792; }
  else if (b < 3072) { W = s4; Wt = d4; K = 1024; N = 4096; lb = b - 2048; }
  else if (b < 4096) { W = s5; Wt = d5; K = 1024; N = 4096; lb = b - 3072; }
  else if (b < 5120) { W = s6; Wt = d6; K = 4096; N = 1024; lb = b - 4096; }
  else               { W = s7; Wt = d7; K = 4096; N = 1024; lb = b - 5120; }
  const int ntn = N >> 6;
  const int n0 = (lb % ntn) * 64, k0 = (lb / ntn) * 64;
  __shared__ float T[64][65];
  const int tx = threadIdx.x & 15, ty = threadIdx.x >> 4;
#pragma unroll
  for (int i = 0; i < 4; ++i) {
    const int r = ty + i * 16;
    const float4 v = *(const float4*)&W[(size_t)(k0 + r) * N + n0 + tx * 4];
    T[r][tx * 4 + 0] = v.x;
    T[r][tx * 4 + 1] = v.y;
    T[r][tx * 4 + 2] = v.z;
    T[r][tx * 4 + 3] = v.w;
  }
  __syncthreads();
  const int rn = threadIdx.x >> 2;
  const int cs = (threadIdx.x & 3) * 16;
  u16 buf[16];
#pragma unroll
  for (int j = 0; j < 16; ++j) buf[j] = f2bf(T[cs + j][rn]);
  u16* dst = &Wt[(size_t)(n0 + rn) * K + k0 + cs];
  *(uint4*)dst = *(uint4*)&buf[0];
  *(uint4*)(dst + 8) = *(uint4*)&buf[8];
}

// ---------------- mod GEMV split-K ------------------------------------------
__global__ __launch_bounds__(256) void mod_gemv_part(
    const float* __restrict__ vec, const float* __restrict__ wi,
    const float* __restrict__ wt, float* __restrict__ part) {
  __shared__ float sv[128];
  const int s = blockIdx.y, kc = blockIdx.z;
  const float* W = s ? wt : wi;
  if (threadIdx.x < 128) {
    float x = vec[kc * 128 + threadIdx.x];
    sv[threadIdx.x] = x / (1.f + __expf(-x));
  }
  __syncthreads();
  const int j = blockIdx.x * 256 + threadIdx.x;
  float acc = 0.f;
#pragma unroll 4
  for (int i = 0; i < 128; ++i)
    acc += sv[i] * W[(size_t)(kc * 128 + i) * 6144 + j];
  part[((size_t)(kc * 2 + s)) * 6144 + j] = acc;
}
__global__ __launch_bounds__(256) void mod_reduce(
    const float* __restrict__ part, const float* __restrict__ bi,
    const float* __restrict__ bt, float* __restrict__ modout) {
  const int idx = blockIdx.x * 256 + threadIdx.x;
  const int s = idx / 6144, j = idx % 6144;
  float a = s ? bt[j] : bi[j];
#pragma unroll
  for (int kc = 0; kc < 8; ++kc) a += part[((size_t)(kc * 2 + s)) * 6144 + j];
  modout[(size_t)s * 6144 + j] = a;
}

// ---------------- fused LN1 + modulate (txt+img, float4) --------------------
__global__ __launch_bounds__(256) void ln_mod2(
    const float* __restrict__ Xtxt, const float* __restrict__ Ximg,
    u16* __restrict__ out, const float* __restrict__ tns,
    const float* __restrict__ tnb, const float* __restrict__ ins,
    const float* __restrict__ inb, const float* __restrict__ modv) {
  __shared__ float red[8];
  const int r = blockIdx.x, tid = threadIdx.x;
  const float* x; const float* ns; const float* nb; const float* mv;
  if (r < LTXT) { x = Xtxt + (size_t)r * DD; ns = tns; nb = tnb; mv = modv + 6144; }
  else { x = Ximg + (size_t)(r - LTXT) * DD; ns = ins; nb = inb; mv = modv; }
  const int c0 = tid * 4;
  const float4 xv = *(const float4*)&x[c0];
  float v[4] = {xv.x, xv.y, xv.z, xv.w};
  float s = 0.f, sq = 0.f;
#pragma unroll
  for (int i = 0; i < 4; ++i) { s += v[i]; sq += v[i] * v[i]; }
#pragma unroll
  for (int o = 32; o; o >>= 1) {
    s += __shfl_xor(s, o);
    sq += __shfl_xor(sq, o);
  }
  if ((tid & 63) == 0) {
    red[tid >> 6] = s;
    red[4 + (tid >> 6)] = sq;
  }
  __syncthreads();
  s = red[0] + red[1] + red[2] + red[3];
  sq = red[4] + red[5] + red[6] + red[7];
  const float mu = s * (1.f / DD);
  const float var = sq * (1.f / DD) - mu * mu;
  const float rstd = rsqrtf(var + 1e-6f);
  const float4 nsv = *(const float4*)&ns[c0];
  const float4 nbv = *(const float4*)&nb[c0];
  const float4 shv = *(const float4*)&mv[c0];
  const float4 scv = *(const float4*)&mv[1024 + c0];
  const float nsa[4] = {nsv.x, nsv.y, nsv.z, nsv.w};
  const float nba[4] = {nbv.x, nbv.y, nbv.z, nbv.w};
  const float sha[4] = {shv.x, shv.y, shv.z, shv.w};
  const float sca[4] = {scv.x, scv.y, scv.z, scv.w};
  ushort4 o4;
  u16 ob[4];
#pragma unroll
  for (int i = 0; i < 4; ++i) {
    const float ln = (v[i] - mu) * rstd * nsa[i] + nba[i];
    ob[i] = f2bf((1.f + sca[i]) * ln + sha[i]);
  }
  o4.x = ob[0]; o4.y = ob[1]; o4.z = ob[2]; o4.w = ob[3];
  *(ushort4*)&out[(size_t)r * DD + c0] = o4;
}

// ------- fused residual1 + LN2 + modulate (txt+img, float4) -----------------
__global__ __launch_bounds__(256) void resid_ln2(
    const float* __restrict__ Xtxt, const float* __restrict__ Ximg,
    const u16* __restrict__ t, const float* __restrict__ modv,
    const float* __restrict__ tns, const float* __restrict__ tnb,
    const float* __restrict__ ins, const float* __restrict__ inb,
    float* __restrict__ otxt, float* __restrict__ oimg,
    u16* __restrict__ hout) {
  __shared__ float red[8];
  const int r = blockIdx.x, tid = threadIdx.x;
  const float* x; const float* ns; const float* nb; const float* mv; float* y;
  if (r < LTXT) {
    x = Xtxt + (size_t)r * DD; ns = tns; nb = tnb; mv = modv + 6144;
    y = otxt + (size_t)r * DD;
  } else {
    x = Ximg + (size_t)(r - LTXT) * DD; ns = ins; nb = inb; mv = modv;
    y = oimg + (size_t)(r - LTXT) * DD;
  }
  const int c0 = tid * 4;
  const float4 xv = *(const float4*)&x[c0];
  const ushort4 tb = *(const ushort4*)&t[(size_t)r * DD + c0];
  const float4 gv = *(const float4*)&mv[2048 + c0];
  float v[4];
  v[0] = xv.x + gv.x * bf2f(tb.x);
  v[1] = xv.y + gv.y * bf2f(tb.y);
  v[2] = xv.z + gv.z * bf2f(tb.z);
  v[3] = xv.w + gv.w * bf2f(tb.w);
  *(float4*)&y[c0] = *(float4*)v;
  float s = 0.f, sq = 0.f;
#pragma unroll
  for (int i = 0; i < 4; ++i) { s += v[i]; sq += v[i] * v[i]; }
#pragma unroll
  for (int o = 32; o; o >>= 1) {
    s += __shfl_xor(s, o);
    sq += __shfl_xor(sq, o);
  }
  if ((tid & 63) == 0) {
    red[tid >> 6] = s;
    red[4 + (tid >> 6)] = sq;
  }
  __syncthreads();
  s = red[0] + red[1] + red[2] + red[3];
  sq = red[4] + red[5] + red[6] + red[7];
  const float mu = s * (1.f / DD);
  const float var = sq * (1.f / DD) - mu * mu;
  const float rstd = rsqrtf(var + 1e-6f);
  const float4 nsv = *(const float4*)&ns[c0];
  const float4 nbv = *(const float4*)&nb[c0];
  const float4 shv = *(const float4*)&mv[3072 + c0];
  const float4 scv = *(const float4*)&mv[4096 + c0];
  const float nsa[4] = {nsv.x, nsv.y, nsv.z, nsv.w};
  const float nba[4] = {nbv.x, nbv.y, nbv.z, nbv.w};
  const float sha[4] = {shv.x, shv.y, shv.z, shv.w};
  const float sca[4] = {scv.x, scv.y, scv.z, scv.w};
  ushort4 o4;
  u16 ob[4];
#pragma unroll
  for (int i = 0; i < 4; ++i) {
    const float ln = (v[i] - mu) * rstd * nsa[i] + nba[i];
    ob[i] = f2bf((1.f + sca[i]) * ln + sha[i]);
  }
  o4.x = ob[0]; o4.y = ob[1]; o4.z = ob[2]; o4.w = ob[3];
  *(ushort4*)&hout[(size_t)r * DD + c0] = o4;
}

// --- bf16 MFMA GEMM, 128x128, BK=32, 8 waves (4x2 of 32x64), 2-buf 2-barrier
// Split-K partials are bf16 (halves reduce-pass HBM traffic).
__global__ __launch_bounds__(512) void gemm_pipe(
    const u16* __restrict__ A, const u16* __restrict__ BtT,
    const u16* __restrict__ BtI, const float* __restrict__ biasT,
    const float* __restrict__ biasI, u16* __restrict__ C,
    u16* __restrict__ Cpart, int K, int Kblk, int N, int gelu) {
  __shared__ __align__(16) u16 As[2][128 * 32];
  __shared__ __align__(16) u16 Bs[2][128 * 32];
  const int tid = threadIdx.x, lane = tid & 63, wave = tid >> 6;  // 0..7
  const int nwg = gridDim.x * gridDim.y;
  const int orig = blockIdx.x + blockIdx.y * gridDim.x;
  const int lb = (orig & 7) * (nwg >> 3) + (orig >> 3);
  const int bn = lb / 20, bm = lb % 20;
  const int kc = blockIdx.z;
  const u16* Bt = (bm < (LTXT / 128)) ? BtT : BtI;
  const int wm = wave >> 1, wn = wave & 1;  // 4 x 2 wave grid
  const int lr = lane & 15, lk = lane >> 4;
  f32x4 acc[2][4] = {};
  const size_t a0 = (size_t)bm * 128;
  const size_t b0 = (size_t)bn * 128;
  const int kbase = kc * Kblk;
  const int NT = Kblk >> 5;
  const int srow = tid >> 2, soff = (tid & 3) * 8;  // 128 rows x 4 chunks

#define STAGE(t, buf)                                                         \
  {                                                                           \
    const int k0_ = kbase + (t) * 32;                                         \
    gload16(&A[(a0 + srow) * K + k0_ + soff], &As[buf][srow * 32 + soff]);    \
    gload16(&Bt[(b0 + srow) * K + k0_ + soff], &Bs[buf][srow * 32 + soff]);   \
  }

  STAGE(0, 0);
  STAGE(1, 1);
  for (int t = 0; t < NT; ++t) {
    if (t + 1 < NT) {
      asm volatile("s_waitcnt vmcnt(2)" ::: "memory");
    } else {
      asm volatile("s_waitcnt vmcnt(0)" ::: "memory");
    }
    __builtin_amdgcn_s_barrier();
    const int b = t & 1;
    bf16x8 af[2], bfv[4];
#pragma unroll
    for (int m = 0; m < 2; ++m)
      af[m] = *(const bf16x8*)&As[b][(wm * 32 + m * 16 + lr) * 32 + lk * 8];
#pragma unroll
    for (int n = 0; n < 4; ++n)
      bfv[n] = *(const bf16x8*)&Bs[b][(wn * 64 + n * 16 + lr) * 32 + lk * 8];
    asm volatile("s_waitcnt lgkmcnt(0)" ::: "memory");
    __builtin_amdgcn_sched_barrier(0);
    __builtin_amdgcn_s_barrier();
    if (t + 2 < NT) STAGE(t + 2, b);
    __builtin_amdgcn_sched_barrier(0);
    __builtin_amdgcn_s_setprio(1);
#pragma unroll
    for (int m = 0; m < 2; ++m)
#pragma unroll
      for (int n = 0; n < 4; ++n)
        acc[m][n] = __builtin_amdgcn_mfma_f32_16x16x32_bf16(af[m], bfv[n],
                                                            acc[m][n], 0, 0, 0);
    __builtin_amdgcn_s_setprio(0);
  }
#undef STAGE

  if (Cpart) {
    u16* dst = Cpart + (size_t)kc * ((size_t)LTOT * N);
#pragma unroll
    for (int n = 0; n < 4; ++n) {
      const int col = bn * 128 + wn * 64 + n * 16 + lr;
#pragma unroll
      for (int m = 0; m < 2; ++m)
#pragma unroll
        for (int r = 0; r < 4; ++r) {
          const size_t row = a0 + wm * 32 + m * 16 + lk * 4 + r;
          dst[row * (size_t)N + col] = f2bf(acc[m][n][r]);
        }
    }
  } else {
    const float* bias = (bm < (LTXT / 128)) ? biasT : biasI;
#pragma unroll
    for (int n = 0; n < 4; ++n) {
      const int col = bn * 128 + wn * 64 + n * 16 + lr;
      const float bv = bias[col];
#pragma unroll
      for (int m = 0; m < 2; ++m)
#pragma unroll
        for (int r = 0; r < 4; ++r) {
          const size_t row = a0 + wm * 32 + m * 16 + lk * 4 + r;
          float v = acc[m][n][r] + bv;
          if (gelu) v = geluf(v);
          C[row * (size_t)N + col] = f2bf(v);
        }
    }
  }
}

// ------- split-K reduce (bf16 partials): C = bf16(sum(part) + bias) ---------
__global__ __launch_bounds__(256) void gemm_reduce(
    const u16* __restrict__ part, const float* __restrict__ bT,
    const float* __restrict__ bI, u16* __restrict__ C, int N, int kcnt) {
  const size_t idx = (size_t)(blockIdx.x * 256 + threadIdx.x) * 4;
  const int row = (int)(idx / N), col = (int)(idx % N);
  float a[4] = {0.f, 0.f, 0.f, 0.f};
  for (int kc = 0; kc < kcnt; ++kc) {
    const ushort4 b = *(const ushort4*)&part[(size_t)kc * LTOT * N + idx];
    a[0] += bf2f(b.x); a[1] += bf2f(b.y); a[2] += bf2f(b.z); a[3] += bf2f(b.w);
  }
  const float* bias = (row < LTXT) ? bT : bI;
  ushort4 o;
  o.x = f2bf(a[0] + bias[col]);
  o.y = f2bf(a[1] + bias[col + 1]);
  o.z = f2bf(a[2] + bias[col + 2]);
  o.w = f2bf(a[3] + bias[col + 3]);
  *(ushort4*)&C[idx] = o;
}

// -- MLP2 split-K reduce (bf16) + bias + gated residual2 into d_out ----------
__global__ __launch_bounds__(256) void gemm_reduce_gate(
    const u16* __restrict__ part, const float* __restrict__ bT,
    const float* __restrict__ bI, const float* __restrict__ modv,
    float* __restrict__ otxt, float* __restrict__ oimg, int kcnt) {
  const size_t idx = (size_t)(blockIdx.x * 256 + threadIdx.x) * 4;
  const int row = (int)(idx >> 10), col = (int)(idx & 1023);
  float a[4] = {0.f, 0.f, 0.f, 0.f};
  for (int kc = 0; kc < kcnt; ++kc) {
    const ushort4 b = *(const ushort4*)&part[(size_t)kc * LTOT * DD + idx];
    a[0] += bf2f(b.x); a[1] += bf2f(b.y); a[2] += bf2f(b.z); a[3] += bf2f(b.w);
  }
  const float* bias; const float* mv; float* o;
  if (row < LTXT) {
    bias = bT; mv = modv + 6144; o = otxt + (size_t)row * DD + col;
  } else {
    bias = bI; mv = modv; o = oimg + (size_t)(row - LTXT) * DD + col;
  }
  const float4 g = *(const float4*)&mv[5120 + col];
  const float4 cur = *(const float4*)o;
  float4 r;
  r.x = cur.x + g.x * (a[0] + bias[col]);
  r.y = cur.y + g.y * (a[1] + bias[col + 1]);
  r.z = cur.z + g.z * (a[2] + bias[col + 2]);
  r.w = cur.w + g.w * (a[3] + bias[col + 3]);
  *(float4*)o = r;
}

// ------- fused scatter + RMS + RoPE for q,k (wave per (h,l)) ----------------
// q is pre-scaled by 0.125*log2(e) so attention softmax runs in exp2 domain.
__global__ __launch_bounds__(256) void scat_rope(
    const u16* __restrict__ qkv, u16* __restrict__ q, u16* __restrict__ k,
    const float* __restrict__ pe, const float* __restrict__ iqs,
    const float* __restrict__ iks, const float* __restrict__ tqs,
    const float* __restrict__ tks) {
  const int gw = (blockIdx.x * 256 + threadIdx.x) >> 6;
  const int lane = threadIdx.x & 63;
  const int l = gw % LTOT, h = gw / LTOT;
  const size_t rb = (size_t)l * 3072 + h * 64 + lane;
  const float qv = bf2f(qkv[rb]);
  const float kv = bf2f(qkv[rb + 1024]);
  const float* qs = (l < LTXT) ? tqs : iqs;
  const float* ks = (l < LTXT) ? tks : iks;
  const float* peb = pe + (size_t)l * 128 + (lane >> 1) * 4 + (lane & 1) * 2;
  const size_t base = ((size_t)h * LTOT + l) * HD + lane;
  {
    float ss = qv * qv;
#pragma unroll
    for (int o = 32; o; o >>= 1) ss += __shfl_xor(ss, o);
    float xn = qv * rsqrtf(ss * (1.f / HD) + 1e-6f) * qs[lane];
    float part = __shfl_xor(xn, 1);
    float x0 = (lane & 1) ? part : xn;
    float x1 = (lane & 1) ? xn : part;
    q[base] = f2bf((peb[0] * x0 + peb[1] * x1) * 0.1803368801111f);
  }
  {
    float ss = kv * kv;
#pragma unroll
    for (int o = 32; o; o >>= 1) ss += __shfl_xor(ss, o);
    float xn = kv * rsqrtf(ss * (1.f / HD) + 1e-6f) * ks[lane];
    float part = __shfl_xor(xn, 1);
    float x0 = (lane & 1) ? part : xn;
    float x1 = (lane & 1) ? xn : part;
    k[base] = f2bf(peb[0] * x0 + peb[1] * x1);
  }
}

// ------- V transpose via LDS: qkv (L,3072) col-block -> VT (H,64,L) ---------
__global__ __launch_bounds__(256) void vt_build(const u16* __restrict__ qkv,
                                                u16* __restrict__ vt) {
  __shared__ u16 T[64][72];
  const int b = blockIdx.x;
  const int h = b & 15, lt = b >> 4;
  const int tid = threadIdx.x;
  const int r = tid >> 3, c8 = (tid & 7) * 8;
  const size_t srcbase = (size_t)(lt * 64) * 3072 + 2048 + h * 64;
  *(uint4*)&T[r][c8] = *(const uint4*)&qkv[srcbase + (size_t)r * 3072 + c8];
  *(uint4*)&T[r + 32][c8] =
      *(const uint4*)&qkv[srcbase + (size_t)(r + 32) * 3072 + c8];
  __syncthreads();
  const int d = tid >> 2, lc = (tid & 3) * 16;
  u16 buf[16];
#pragma unroll
  for (int j = 0; j < 16; ++j) buf[j] = T[lc + j][d];
  u16* dst = &vt[((size_t)h * 64 + d) * LTOT + lt * 64 + lc];
  *(uint4*)dst = *(uint4*)&buf[0];
  *(uint4*)(dst + 8) = *(uint4*)&buf[8];
}

// ---- MFMA flash attention: 8 waves x 16q, 128 q/block, split-KV {1,2,4} ----
// MAXLESS softmax: Q,K are unit-RMS (norm=8; RoPE is a rotation) so
// |score_log2| <= 64*0.125*log2e = 11.54 -> P = exp2(s) directly is safe in
// fp32/bf16 (max ~2980, min ~3.4e-4). No max tree, no rescale, no shfl.
// l via ones-row MFMA. Partials: 64 bf16 + f32 l per (q,h), stride-80 u16.
template <int SPLIT>
__global__ __launch_bounds__(512) void attn_mfma(
    const u16* __restrict__ Q, const u16* __restrict__ Kg,
    const u16* __restrict__ VT, u16* __restrict__ out,
    u16* __restrict__ part) {
  constexpr int LOG = (SPLIT == 4) ? 2 : ((SPLIT == 2) ? 1 : 0);
  __shared__ __align__(16) u16 Ks[2][64 * 64];
  __shared__ __align__(16) u16 Vs[2][64 * 64];
  const int tid = threadIdx.x, lane = tid & 63, w = tid >> 6;  // w = 0..7
  const int lr = lane & 15, lk = lane >> 4;
  const int blk = blockIdx.x;
  const int h = ((blk & 7) << 1) | ((blk >> 3) & 1);
  const int half = (blk >> 4) & (SPLIT - 1);
  const int q0 = (blk >> (4 + LOG)) * 128;
  const size_t hb = (size_t)h * LTOT;
  char* KsB0 = (char*)&Ks[0][0];
  char* VsB0 = (char*)&Vs[0][0];

  union { u16 u[8]; bf16x8 v; } one8;
#pragma unroll
  for (int i = 0; i < 8; ++i) one8.u[i] = 0x3F80;  // bf16 1.0

  const int q = q0 + w * 16 + lr;
  const bf16x8 qa0 = *(const bf16x8*)&Q[(hb + q) * HD + lk * 8];
  const bf16x8 qa1 = *(const bf16x8*)&Q[(hb + q) * HD + 32 + lk * 8];

  const int srow = tid >> 3;  // 0..63
  const int soff = tid & 7;
  const int NT = (LTOT / SPLIT) / 64;
  const int kstart = half * (LTOT / SPLIT);

  f32x4 acc[4] = {};
  f32x4 accL = {};  // ones-row MFMA accumulator; [0] == running l
  uint4 kst, vst;

  kst = *(const uint4*)&Kg[(hb + kstart + srow) * HD + soff * 8];
  vst = *(const uint4*)&VT[((size_t)h * HD + srow) * LTOT + kstart + soff * 8];
  *(uint4*)(KsB0 + ((srow * 128 + soff * 16) ^ SWZ(srow))) = kst;
  *(uint4*)(VsB0 + ((srow * 128 + soff * 16) ^ SWZ(srow))) = vst;
  __syncthreads();

  for (int t = 0; t < NT; ++t) {
    char* KsC = KsB0 + (t & 1) * 8192;
    char* VsC = VsB0 + (t & 1) * 8192;
    if (t + 1 < NT) {
      const int k0n = kstart + (t + 1) * 64;
      kst = *(const uint4*)&Kg[(hb + k0n + srow) * HD + soff * 8];
      vst = *(const uint4*)&VT[((size_t)h * HD + srow) * LTOT + k0n + soff * 8];
    }
    f32x4 s[4];
    __builtin_amdgcn_s_setprio(1);
#pragma unroll
    for (int g = 0; g < 4; ++g) {
      const int kr = (lr >> 2) * 8 + (g & 1) * 4 + (lr & 3) + (g >> 1) * 32;
      const int sw = SWZ(kr);
      const bf16x8 ka0 = *(const bf16x8*)(KsC + ((kr * 128 + lk * 16) ^ sw));
      const bf16x8 ka1 = *(const bf16x8*)(KsC + ((kr * 128 + 64 + lk * 16) ^ sw));
      f32x4 z = {0.f, 0.f, 0.f, 0.f};
      z = __builtin_amdgcn_mfma_f32_16x16x32_bf16(ka0, qa0, z, 0, 0, 0);
      z = __builtin_amdgcn_mfma_f32_16x16x32_bf16(ka1, qa1, z, 0, 0, 0);
      s[g] = z;
    }
    __builtin_amdgcn_s_setprio(0);
    // maxless: P = exp2(s), bounded by construction
    float p[4][4];
#pragma unroll
    for (int g = 0; g < 4; ++g)
#pragma unroll
      for (int r = 0; r < 4; ++r) p[g][r] = fexp2(s[g][r]);
    union { uint32_t u[4]; bf16x8 v; } pb0, pb1;
    pb0.u[0] = cvtpk(p[0][0], p[0][1]);
    pb0.u[1] = cvtpk(p[0][2], p[0][3]);
    pb0.u[2] = cvtpk(p[1][0], p[1][1]);
    pb0.u[3] = cvtpk(p[1][2], p[1][3]);
    pb1.u[0] = cvtpk(p[2][0], p[2][1]);
    pb1.u[1] = cvtpk(p[2][2], p[2][3]);
    pb1.u[2] = cvtpk(p[3][0], p[3][1]);
    pb1.u[3] = cvtpk(p[3][2], p[3][3]);
    __builtin_amdgcn_s_setprio(1);
    // l via ones-row: accL[i][q] += sum_k P[k][q] (all rows identical)
    accL = __builtin_amdgcn_mfma_f32_16x16x32_bf16(one8.v, pb0.v, accL, 0, 0, 0);
    accL = __builtin_amdgcn_mfma_f32_16x16x32_bf16(one8.v, pb1.v, accL, 0, 0, 0);
#pragma unroll
    for (int dt = 0; dt < 4; ++dt) {
      const int vr = dt * 16 + lr;
      const int sw = SWZ(vr);
      const bf16x8 va0 = *(const bf16x8*)(VsC + ((vr * 128 + lk * 16) ^ sw));
      const bf16x8 va1 = *(const bf16x8*)(VsC + ((vr * 128 + 64 + lk * 16) ^ sw));
      acc[dt] = __builtin_amdgcn_mfma_f32_16x16x32_bf16(va0, pb0.v, acc[dt], 0, 0, 0);
      acc[dt] = __builtin_amdgcn_mfma_f32_16x16x32_bf16(va1, pb1.v, acc[dt], 0, 0, 0);
    }
    __builtin_amdgcn_s_setprio(0);
    if (t + 1 < NT) {
      char* KsN = KsB0 + ((t + 1) & 1) * 8192;
      char* VsN = VsB0 + ((t + 1) & 1) * 8192;
      *(uint4*)(KsN + ((srow * 128 + soff * 16) ^ SWZ(srow))) = kst;
      *(uint4*)(VsN + ((srow * 128 + soff * 16) ^ SWZ(srow))) = vst;
      __syncthreads();
    }
  }
  const float l_run = accL[0];
  if (SPLIT > 1) {
    u16* pr = part + (((size_t)(half * LTOT) + q) * 16 + h) * 80;
#pragma unroll
    for (int dt = 0; dt < 4; ++dt) {
      uint2 o;
      o.x = cvtpk(acc[dt][0], acc[dt][1]);
      o.y = cvtpk(acc[dt][2], acc[dt][3]);
      *(uint2*)&pr[dt * 16 + lk * 4] = o;
    }
    if (lk == 0) {
      *(float*)&pr[64] = l_run;
    }
  } else {
    __syncthreads();
    const float inv = 1.f / l_run;
    char* ob = KsB0 + w * 2048;
    const int esw = (lr & 7) << 4;
#pragma unroll
    for (int dt = 0; dt < 4; ++dt) {
      const uint32_t a = cvtpk(acc[dt][0] * inv, acc[dt][1] * inv);
      const uint32_t b2 = cvtpk(acc[dt][2] * inv, acc[dt][3] * inv);
      const int ad = lr * 128 + dt * 32 + lk * 8;
      *(uint32_t*)(ob + (ad ^ esw)) = a;
      *(uint32_t*)(ob + ((ad + 4) ^ esw)) = b2;
    }
    __syncthreads();
    const int row = lane >> 2, ch = lane & 3;
    const int rsw = (row & 7) << 4;
    const uint4 o0 = *(const uint4*)(ob + ((row * 128 + ch * 32) ^ rsw));
    const uint4 o1 = *(const uint4*)(ob + ((row * 128 + ch * 32 + 16) ^ rsw));
    u16* orow = &out[(size_t)(q0 + w * 16 + row) * DD + h * HD + ch * 16];
    *(uint4*)orow = o0;
    *(uint4*)(orow + 8) = o1;
  }
}

// ---- merge SPLIT KV parts (bf16, shared zero-max basis) -> bf16 out --------
template <int SPLIT>
__global__ __launch_bounds__(256) void attn_merge(const u16* __restrict__ part,
                                                  u16* __restrict__ out) {
  const int idx = blockIdx.x * 256 + threadIdx.x;
  const int d4 = idx & 15, h = (idx >> 4) & 15, q = idx >> 8;
  const u16* bp[SPLIT];
  float denom = 0.f;
#pragma unroll
  for (int s = 0; s < SPLIT; ++s) {
    bp[s] = part + (((size_t)(s * LTOT) + q) * 16 + h) * 80;
    denom += *(const float*)&bp[s][64];
  }
  const float inv = 1.f / denom;
  float r[4] = {0.f, 0.f, 0.f, 0.f};
#pragma unroll
  for (int s = 0; s < SPLIT; ++s) {
    const uint2 xr = *(const uint2*)&bp[s][d4 * 4];
    const u16* xp = (const u16*)&xr;
    r[0] += bf2f(xp[0]);
    r[1] += bf2f(xp[1]);
    r[2] += bf2f(xp[2]);
    r[3] += bf2f(xp[3]);
  }
  uint2 o;
  o.x = cvtpk(r[0] * inv, r[1] * inv);
  o.y = cvtpk(r[2] * inv, r[3] * inv);
  *(uint2*)&out[(size_t)q * DD + h * HD + d4 * 4] = o;
}

// ---------------- gated residual (fallback path only) -----------------------
__global__ __launch_bounds__(256) void resid_gate(
    const float* __restrict__ xin, const u16* __restrict__ t,
    const float* __restrict__ g, float* __restrict__ out, int n4) {
  const int idx = blockIdx.x * 256 + threadIdx.x;
  if (idx >= n4) return;
  const int col = (idx * 4) & (DD - 1);
  const float4 a = ((const float4*)xin)[idx];
  const ushort4 tb = ((const ushort4*)t)[idx];
  const float4 gg = *(const float4*)&g[col];
  float4 r;
  r.x = a.x + gg.x * bf2f(tb.x);
  r.y = a.y + gg.y * bf2f(tb.y);
  r.z = a.z + gg.z * bf2f(tb.z);
  r.w = a.w + gg.w * bf2f(tb.w);
  ((float4*)out)[idx] = r;
}

extern "C" void kernel_launch(void* const* d_in, const int* in_sizes, int n_in,
                              void* d_out, int out_size, void* d_ws,
                              size_t ws_size, hipStream_t stream) {
  const float* img = (const float*)d_in[0];
  const float* txt = (const float*)d_in[1];
  const float* vec = (const float*)d_in[2];
  const float* pe = (const float*)d_in[3];
  const float* i_mod_w = (const float*)d_in[4];
  const float* i_mod_b = (const float*)d_in[5];
  const float* i_n1s = (const float*)d_in[6];
  const float* i_n1b = (const float*)d_in[7];
  const float* i_qkv_w = (const float*)d_in[8];
  const float* i_qkv_b = (const float*)d_in[9];
  const float* i_qs = (const float*)d_in[10];
  const float* i_ks = (const float*)d_in[11];
  const float* i_proj_w = (const float*)d_in[12];
  const float* i_proj_b = (const float*)d_in[13];
  const float* i_n2s = (const float*)d_in[14];
  const float* i_n2b = (const float*)d_in[15];
  const float* i_w1 = (const float*)d_in[16];
  const float* i_b1 = (const float*)d_in[17];
  const float* i_w2 = (const float*)d_in[18];
  const float* i_b2 = (const float*)d_in[19];
  const float* t_mod_w = (const float*)d_in[20];
  const float* t_mod_b = (const float*)d_in[21];
  const float* t_n1s = (const float*)d_in[22];
  const float* t_n1b = (const float*)d_in[23];
  const float* t_qkv_w = (const float*)d_in[24];
  const float* t_qkv_b = (const float*)d_in[25];
  const float* t_qs = (const float*)d_in[26];
  const float* t_ks = (const float*)d_in[27];
  const float* t_proj_w = (const float*)d_in[28];
  const float* t_proj_b = (const float*)d_in[29];
  const float* t_n2s = (const float*)d_in[30];
  const float* t_n2b = (const float*)d_in[31];
  const float* t_w1 = (const float*)d_in[32];
  const float* t_b1 = (const float*)d_in[33];
  const float* t_w2 = (const float*)d_in[34];
  const float* t_b2 = (const float*)d_in[35];

  const size_t LD = (size_t)LTOT * DD;
  uint8_t* p = (uint8_t*)d_ws;
  float* modb = (float*)p;           p += 64 * 1024;
  float* part = (float*)p;           p += 512 * 1024;
  u16* tqkvT = (u16*)p;              p += (size_t)3072 * 1024 * 2;
  u16* iqkvT = (u16*)p;              p += (size_t)3072 * 1024 * 2;
  u16* tprojT = (u16*)p;             p += (size_t)1024 * 1024 * 2;
  u16* iprojT = (u16*)p;             p += (size_t)1024 * 1024 * 2;
  u16* tw1T = (u16*)p;               p += (size_t)4096 * 1024 * 2;
  u16* iw1T = (u16*)p;               p += (size_t)4096 * 1024 * 2;
  u16* tw2T = (u16*)p;               p += (size_t)1024 * 4096 * 2;
  u16* iw2T = (u16*)p;               p += (size_t)1024 * 4096 * 2;
  u16* actA = (u16*)p;               p += LD * 2;
  u16* actB = (u16*)p;               p += (size_t)LTOT * DMLP * 2;
  u16* actC = (u16*)p;               p += LD * 2 * 3;
  u16* gpart = (u16*)p;
  const size_t used = (size_t)(p - (uint8_t*)d_ws);
  const size_t avail = ws_size > used ? ws_size - used : 0;
  const size_t attn_need2 = (size_t)2 * LTOT * 16 * 80 * sizeof(u16);
  const size_t attn_need4 = 2 * attn_need2;
  const int attn_split = avail >= attn_need4 ? 4 : (avail >= attn_need2 ? 2 : 1);
  const int kc_proj = avail >= 2 * LD * sizeof(u16) ? 2 : 1;
  const int kc_mlp2 = avail >= 4 * LD * sizeof(u16)
                          ? 4
                          : (avail >= 2 * LD * sizeof(u16) ? 2 : 1);
  float* out_img = (float*)d_out;
  float* out_txt = out_img + (size_t)LIMG * DD;

  // 0. weight transpose+cast
  wcast_all<<<6144, 256, 0, stream>>>(t_qkv_w, i_qkv_w, t_proj_w, i_proj_w,
                                      t_w1, i_w1, t_w2, i_w2, tqkvT, iqkvT,
                                      tprojT, iprojT, tw1T, iw1T, tw2T, iw2T);
  // 1. modulation
  mod_gemv_part<<<dim3(24, 2, 8), 256, 0, stream>>>(vec, i_mod_w, t_mod_w, part);
  mod_reduce<<<48, 256, 0, stream>>>(part, i_mod_b, t_mod_b, modb);
  // 2. LN1+mod -> actA
  ln_mod2<<<LTOT, 256, 0, stream>>>(txt, img, actA, t_n1s, t_n1b, i_n1s, i_n1b,
                                    modb);
  // 3. QKV GEMM -> actB
  gemm_pipe<<<dim3(24, 20, 1), 512, 0, stream>>>(actA, tqkvT, iqkvT, t_qkv_b,
                                                 i_qkv_b, actB, nullptr, 1024,
                                                 1024, 3072, 0);
  // 4. q,k scatter + RMS + RoPE ; V transpose
  scat_rope<<<10240, 256, 0, stream>>>(actB, actC, actC + LD, pe, i_qs, i_ks,
                                       t_qs, t_ks);
  vt_build<<<640, 256, 0, stream>>>(actB, actC + 2 * LD);
  // 6. attention (8 waves x 16q, split-KV, maxless exp2 softmax) -> actA
  if (attn_split == 4) {
    attn_mfma<4><<<1280, 512, 0, stream>>>(actC, actC + LD, actC + 2 * LD,
                                           actA, gpart);
    attn_merge<4><<<2560, 256, 0, stream>>>(gpart, actA);
  } else if (attn_split == 2) {
    attn_mfma<2><<<640, 512, 0, stream>>>(actC, actC + LD, actC + 2 * LD,
                                          actA, gpart);
    attn_merge<2><<<2560, 256, 0, stream>>>(gpart, actA);
  } else {
    attn_mfma<1><<<320, 512, 0, stream>>>(actC, actC + LD, actC + 2 * LD, actA,
                                          nullptr);
  }
  // 7. proj GEMM (split-K, bf16 partials) -> actC
  if (kc_proj > 1) {
    gemm_pipe<<<dim3(8, 20, kc_proj), 512, 0, stream>>>(
        actA, tprojT, iprojT, nullptr, nullptr, nullptr, gpart, 1024,
        1024 / kc_proj, 1024, 0);
    gemm_reduce<<<2560, 256, 0, stream>>>(gpart, t_proj_b, i_proj_b, actC,
                                          1024, kc_proj);
  } else {
    gemm_pipe<<<dim3(8, 20, 1), 512, 0, stream>>>(actA, tprojT, iprojT,
                                                  t_proj_b, i_proj_b, actC,
                                                  nullptr, 1024, 1024, 1024, 0);
  }
  // 8+9. fused residual1 + LN2+mod
  resid_ln2<<<LTOT, 256, 0, stream>>>(txt, img, actC, modb, t_n2s, t_n2b,
                                      i_n2s, i_n2b, out_txt, out_img,
                                      actC + LD);
  // 10. MLP1+GELU -> actB
  gemm_pipe<<<dim3(32, 20, 1), 512, 0, stream>>>(actC + LD, tw1T, iw1T, t_b1,
                                                 i_b1, actB, nullptr, 1024,
                                                 1024, 4096, 1);
  // 11+12. MLP2 (split-K, bf16 partials) + fused reduce+gate -> d_out
  if (kc_mlp2 > 1) {
    gemm_pipe<<<dim3(8, 20, kc_mlp2), 512, 0, stream>>>(
        actB, tw2T, iw2T, nullptr, nullptr, nullptr, gpart, 4096,
        4096 / kc_mlp2, 1024, 0);
    gemm_reduce_gate<<<2560, 256, 0, stream>>>(gpart, t_b2, i_b2, modb,
                                               out_txt, out_img, kc_mlp2);
  } else {
    gemm_pipe<<<dim3(8, 20, 1), 512, 0, stream>>>(actB, tw2T, iw2T, t_b2, i_b2,
                                                  actC + 2 * LD, nullptr, 4096,
                                                  4096, 1024, 0);
    resid_gate<<<2048, 256, 0, stream>>>(out_img,
                                         actC + 2 * LD + (size_t)LTXT * DD,
                                         modb + 5120, out_img, LIMG * DD / 4);
    resid_gate<<<512, 256, 0, stream>>>(out_txt, actC + 2 * LD,
                                        modb + 6144 + 5120, out_txt,
                                        LTXT * DD / 4);
  }
}